// Round 1
// baseline (2866.138 us; speedup 1.0000x reference)
//
#include <hip/hip_runtime.h>
#include <hip/hip_bf16.h>

#define NNODES 50000
#define DIM 128   // both SPMMs run on 128 dims after the W2 reorder

// ---------------- degree / dinv ----------------
__global__ void deg_init(int* __restrict__ deg, int n) {
    int i = blockIdx.x * blockDim.x + threadIdx.x;
    if (i < n) deg[i] = 1;  // self loop
}

__global__ void deg_count(const int* __restrict__ row, int* __restrict__ deg, int nE) {
    int e = blockIdx.x * blockDim.x + threadIdx.x;
    if (e < nE) atomicAdd(&deg[row[e]], 1);
}

__global__ void calc_dinv(const int* __restrict__ deg, float* __restrict__ dinv, int n) {
    int i = blockIdx.x * blockDim.x + threadIdx.x;
    if (i < n) dinv[i] = rsqrtf((float)deg[i]);
}

// ---------------- SPMM ----------------
// Y[i,:] = dinv[i]^2 * X[i,:] (+ bias)   -- the self-loop term, also initializes Y
__global__ void spmm_init(const float* __restrict__ X, const float* __restrict__ dinv,
                          const float* __restrict__ bias, float* __restrict__ Y, int n_nodes) {
    int tid = blockIdx.x * blockDim.x + threadIdx.x;   // one float4 per thread
    int total = n_nodes * (DIM / 4);
    if (tid >= total) return;
    int i = tid >> 5;        // node (DIM/4 == 32)
    int l = tid & 31;        // float4 slot within row
    float s = dinv[i] * dinv[i];
    float4 xv = reinterpret_cast<const float4*>(X)[tid];
    float4 o;
    o.x = s * xv.x; o.y = s * xv.y; o.z = s * xv.z; o.w = s * xv.w;
    if (bias) {
        float4 b = reinterpret_cast<const float4*>(bias)[l];
        o.x += b.x; o.y += b.y; o.z += b.z; o.w += b.w;
    }
    reinterpret_cast<float4*>(Y)[tid] = o;
}

// Y[row[e],:] += dinv[row]*dinv[col] * X[col[e],:]   (32 threads per edge, float4 each)
__global__ void spmm_edges(const int* __restrict__ row, const int* __restrict__ col,
                           const float* __restrict__ dinv, const float* __restrict__ X,
                           float* __restrict__ Y, int nE) {
    int tid = blockIdx.x * blockDim.x + threadIdx.x;
    int e = tid >> 5;
    int l = tid & 31;
    if (e >= nE) return;
    int r = row[e], c = col[e];
    float v = dinv[r] * dinv[c];
    float4 xv = reinterpret_cast<const float4*>(X)[(size_t)c * 32 + l];
    float* yr = Y + (size_t)r * DIM + l * 4;
    atomicAdd(yr + 0, v * xv.x);
    atomicAdd(yr + 1, v * xv.y);
    atomicAdd(yr + 2, v * xv.z);
    atomicAdd(yr + 3, v * xv.w);
}

// ---------------- GEMM (NT): C[m,n] = sum_k A[m,k]*B[n,k] (+bias[n]) (relu) ----------------
template <bool RELU, bool BIAS>
__global__ __launch_bounds__(256) void gemm_nt(const float* __restrict__ A, const float* __restrict__ B,
                        const float* __restrict__ bias, float* __restrict__ C,
                        int M, int N, int K) {
    constexpr int BM = 64, BN = 64, BK = 16;
    __shared__ float As[BK][BM + 4];
    __shared__ float Bs[BK][BN + 4];
    int m0 = blockIdx.y * BM, n0 = blockIdx.x * BN;
    int tid = threadIdx.x;          // 256 threads
    int tx = tid & 15, ty = tid >> 4;
    float acc[4][4] = {};

    for (int k0 = 0; k0 < K; k0 += BK) {
        // A tile: 64 rows x 16 k -> one float4 per thread
        {
            int r = tid >> 2;          // 0..63
            int q = tid & 3;           // 0..3  (k quad)
            int gm = m0 + r;
            float4 v = make_float4(0.f, 0.f, 0.f, 0.f);
            if (gm < M) v = *reinterpret_cast<const float4*>(&A[(size_t)gm * K + k0 + q * 4]);
            As[q * 4 + 0][r] = v.x; As[q * 4 + 1][r] = v.y;
            As[q * 4 + 2][r] = v.z; As[q * 4 + 3][r] = v.w;
            float4 w = *reinterpret_cast<const float4*>(&B[(size_t)(n0 + r) * K + k0 + q * 4]);
            Bs[q * 4 + 0][r] = w.x; Bs[q * 4 + 1][r] = w.y;
            Bs[q * 4 + 2][r] = w.z; Bs[q * 4 + 3][r] = w.w;
        }
        __syncthreads();
        #pragma unroll
        for (int kk = 0; kk < BK; ++kk) {
            float4 a = *reinterpret_cast<const float4*>(&As[kk][ty * 4]);
            float4 b = *reinterpret_cast<const float4*>(&Bs[kk][tx * 4]);
            acc[0][0] += a.x * b.x; acc[0][1] += a.x * b.y; acc[0][2] += a.x * b.z; acc[0][3] += a.x * b.w;
            acc[1][0] += a.y * b.x; acc[1][1] += a.y * b.y; acc[1][2] += a.y * b.z; acc[1][3] += a.y * b.w;
            acc[2][0] += a.z * b.x; acc[2][1] += a.z * b.y; acc[2][2] += a.z * b.z; acc[2][3] += a.z * b.w;
            acc[3][0] += a.w * b.x; acc[3][1] += a.w * b.y; acc[3][2] += a.w * b.z; acc[3][3] += a.w * b.w;
        }
        __syncthreads();
    }

    float4 bv = make_float4(0.f, 0.f, 0.f, 0.f);
    if (BIAS) bv = *reinterpret_cast<const float4*>(&bias[n0 + tx * 4]);
    #pragma unroll
    for (int i = 0; i < 4; ++i) {
        int gm = m0 + ty * 4 + i;
        if (gm >= M) break;
        float4 o;
        o.x = acc[i][0] + bv.x; o.y = acc[i][1] + bv.y;
        o.z = acc[i][2] + bv.z; o.w = acc[i][3] + bv.w;
        if (RELU) {
            o.x = fmaxf(o.x, 0.f); o.y = fmaxf(o.y, 0.f);
            o.z = fmaxf(o.z, 0.f); o.w = fmaxf(o.w, 0.f);
        }
        *reinterpret_cast<float4*>(&C[(size_t)gm * N + n0 + tx * 4]) = o;
    }
}

extern "C" void kernel_launch(void* const* d_in, const int* in_sizes, int n_in,
                              void* d_out, int out_size, void* d_ws, size_t ws_size,
                              hipStream_t stream) {
    const float* x  = (const float*)d_in[0];
    const int*   ei = (const int*)d_in[1];
    const float* W1 = (const float*)d_in[2];
    const float* b1 = (const float*)d_in[3];
    const float* W2 = (const float*)d_in[4];
    const float* b2 = (const float*)d_in[5];
    float* out = (float*)d_out;

    const int N = NNODES;
    const int E = in_sizes[1] / 2;
    const int IN_D = 128, HID = 256;
    const int* row = ei;
    const int* col = ei + E;

    // workspace carve-out
    char* ws = (char*)d_ws;
    int*   deg  = (int*)ws;                              // N ints
    float* dinv = (float*)(ws + (256 << 10));            // N floats
    float* y1   = (float*)(ws + (512 << 10));            // N*128 floats (25.6 MB), reused as z
    float* h    = (float*)(ws + (512 << 10) + ((size_t)26 << 20)); // N*256 floats (51.2 MB)
    float* z    = y1;

    const int TB = 256;
    // 1) degree + dinv
    deg_init<<<(N + TB - 1) / TB, TB, 0, stream>>>(deg, N);
    deg_count<<<(E + TB - 1) / TB, TB, 0, stream>>>(row, deg, E);
    calc_dinv<<<(N + TB - 1) / TB, TB, 0, stream>>>(deg, dinv, N);

    // 2) y1 = A' x   (self-loop init + edge atomics)
    spmm_init<<<(N * 32 + TB - 1) / TB, TB, 0, stream>>>(x, dinv, nullptr, y1, N);
    spmm_edges<<<((size_t)E * 32 + TB - 1) / TB, TB, 0, stream>>>(row, col, dinv, x, y1, E);

    // 3) h = relu(y1 @ W1^T + b1)   [N,128] -> [N,256]
    {
        dim3 grid(HID / 64, (N + 63) / 64);
        gemm_nt<true, true><<<grid, 256, 0, stream>>>(y1, W1, b1, h, N, HID, IN_D);
    }

    // 4) z = h @ W2^T               [N,256] -> [N,128]   (b2 deferred past SPMM2)
    {
        dim3 grid(IN_D / 64, (N + 63) / 64);
        gemm_nt<false, false><<<grid, 256, 0, stream>>>(h, W2, nullptr, z, N, IN_D, HID);
    }

    // 5) out = A' z + b2
    spmm_init<<<(N * 32 + TB - 1) / TB, TB, 0, stream>>>(z, dinv, b2, out, N);
    spmm_edges<<<((size_t)E * 32 + TB - 1) / TB, TB, 0, stream>>>(row, col, dinv, z, out, E);
}

// Round 2
// 440.344 us; speedup vs baseline: 6.5089x; 6.5089x over previous
//
#include <hip/hip_runtime.h>
#include <hip/hip_bf16.h>

#define NNODES 50000
#define DIM 128   // both SPMMs run on 128 dims after the W2 reorder

// ---------------- degree count ----------------
__global__ void cnt_init(int* __restrict__ cnt, int n) {
    int i = blockIdx.x * blockDim.x + threadIdx.x;
    if (i < n) cnt[i] = 0;
}

__global__ void deg_count(const int* __restrict__ row, int* __restrict__ cnt, int nE) {
    int e = blockIdx.x * blockDim.x + threadIdx.x;
    if (e < nE) atomicAdd(&cnt[row[e]], 1);
}

// dinv[i] = rsqrt(cnt[i] + 1)   (+1 = self loop; always >= 1 so clip is a no-op)
__global__ void calc_dinv(const int* __restrict__ cnt, float* __restrict__ dinv, int n) {
    int i = blockIdx.x * blockDim.x + threadIdx.x;
    if (i < n) dinv[i] = rsqrtf((float)(cnt[i] + 1));
}

// ---------------- exclusive scan of cnt -> row_ptr (single block) ----------------
__global__ __launch_bounds__(1024) void scan_kernel(const int* __restrict__ cnt,
                                                    int* __restrict__ row_ptr,
                                                    int* __restrict__ cursor, int n) {
    __shared__ int sums[1024];
    int t = threadIdx.x;
    int chunk = (n + 1023) >> 10;
    int s = t * chunk;
    int e = min(n, s + chunk);
    int local = 0;
    for (int i = s; i < e; ++i) local += cnt[i];
    sums[t] = local;
    __syncthreads();
    // Hillis-Steele inclusive scan over 1024 entries
    for (int off = 1; off < 1024; off <<= 1) {
        int v = (t >= off) ? sums[t - off] : 0;
        __syncthreads();
        sums[t] += v;
        __syncthreads();
    }
    int run = (t == 0) ? 0 : sums[t - 1];
    for (int i = s; i < e; ++i) {
        row_ptr[i] = run;
        cursor[i] = run;
        run += cnt[i];
    }
    if (t == 1023) row_ptr[n] = run;
}

// ---------------- scatter edges into CSR ----------------
__global__ void scatter_edges(const int* __restrict__ row, const int* __restrict__ col,
                              int* __restrict__ cursor, int* __restrict__ cols, int nE) {
    int e = blockIdx.x * blockDim.x + threadIdx.x;
    if (e < nE) {
        int pos = atomicAdd(&cursor[row[e]], 1);
        cols[pos] = col[e];
    }
}

// ---------------- CSR SPMM (gather, no fp atomics) ----------------
// Y[i,:] = dinv[i] * ( dinv[i]*X[i,:] + sum_j dinv[c_j]*X[c_j,:] ) (+ bias)
__global__ __launch_bounds__(256) void spmm_csr(const int* __restrict__ row_ptr,
                         const int* __restrict__ cols, const float* __restrict__ dinv,
                         const float* __restrict__ X, const float* __restrict__ bias,
                         float* __restrict__ Y, int n) {
    int tid = blockIdx.x * blockDim.x + threadIdx.x;
    int i = tid >> 5;        // node
    int l = tid & 31;        // float4 slot (DIM/4 == 32)
    if (i >= n) return;
    const float4* X4 = reinterpret_cast<const float4*>(X);
    float di = dinv[i];
    float4 xv = X4[(size_t)i * 32 + l];
    float4 acc;
    acc.x = di * xv.x; acc.y = di * xv.y; acc.z = di * xv.z; acc.w = di * xv.w;
    int s = row_ptr[i], e = row_ptr[i + 1];
    int j = s;
    for (; j + 1 < e; j += 2) {
        int c0 = cols[j], c1 = cols[j + 1];
        float w0 = dinv[c0], w1 = dinv[c1];
        float4 v0 = X4[(size_t)c0 * 32 + l];
        float4 v1 = X4[(size_t)c1 * 32 + l];
        acc.x += w0 * v0.x + w1 * v1.x;
        acc.y += w0 * v0.y + w1 * v1.y;
        acc.z += w0 * v0.z + w1 * v1.z;
        acc.w += w0 * v0.w + w1 * v1.w;
    }
    if (j < e) {
        int c0 = cols[j];
        float w0 = dinv[c0];
        float4 v0 = X4[(size_t)c0 * 32 + l];
        acc.x += w0 * v0.x; acc.y += w0 * v0.y;
        acc.z += w0 * v0.z; acc.w += w0 * v0.w;
    }
    acc.x *= di; acc.y *= di; acc.z *= di; acc.w *= di;
    if (bias) {
        float4 b = reinterpret_cast<const float4*>(bias)[l];
        acc.x += b.x; acc.y += b.y; acc.z += b.z; acc.w += b.w;
    }
    reinterpret_cast<float4*>(Y)[(size_t)i * 32 + l] = acc;
}

// ---------------- GEMM (NT): C[m,n] = sum_k A[m,k]*B[n,k] (+bias[n]) (relu) ----------------
template <bool RELU, bool BIAS>
__global__ __launch_bounds__(256) void gemm_nt(const float* __restrict__ A, const float* __restrict__ B,
                        const float* __restrict__ bias, float* __restrict__ C,
                        int M, int N, int K) {
    constexpr int BM = 64, BN = 64, BK = 16;
    __shared__ float As[BK][BM + 4];
    __shared__ float Bs[BK][BN + 4];
    int m0 = blockIdx.y * BM, n0 = blockIdx.x * BN;
    int tid = threadIdx.x;          // 256 threads
    int tx = tid & 15, ty = tid >> 4;
    float acc[4][4] = {};

    for (int k0 = 0; k0 < K; k0 += BK) {
        {
            int r = tid >> 2;          // 0..63
            int q = tid & 3;           // 0..3  (k quad)
            int gm = m0 + r;
            float4 v = make_float4(0.f, 0.f, 0.f, 0.f);
            if (gm < M) v = *reinterpret_cast<const float4*>(&A[(size_t)gm * K + k0 + q * 4]);
            As[q * 4 + 0][r] = v.x; As[q * 4 + 1][r] = v.y;
            As[q * 4 + 2][r] = v.z; As[q * 4 + 3][r] = v.w;
            float4 w = *reinterpret_cast<const float4*>(&B[(size_t)(n0 + r) * K + k0 + q * 4]);
            Bs[q * 4 + 0][r] = w.x; Bs[q * 4 + 1][r] = w.y;
            Bs[q * 4 + 2][r] = w.z; Bs[q * 4 + 3][r] = w.w;
        }
        __syncthreads();
        #pragma unroll
        for (int kk = 0; kk < BK; ++kk) {
            float4 a = *reinterpret_cast<const float4*>(&As[kk][ty * 4]);
            float4 b = *reinterpret_cast<const float4*>(&Bs[kk][tx * 4]);
            acc[0][0] += a.x * b.x; acc[0][1] += a.x * b.y; acc[0][2] += a.x * b.z; acc[0][3] += a.x * b.w;
            acc[1][0] += a.y * b.x; acc[1][1] += a.y * b.y; acc[1][2] += a.y * b.z; acc[1][3] += a.y * b.w;
            acc[2][0] += a.z * b.x; acc[2][1] += a.z * b.y; acc[2][2] += a.z * b.z; acc[2][3] += a.z * b.w;
            acc[3][0] += a.w * b.x; acc[3][1] += a.w * b.y; acc[3][2] += a.w * b.z; acc[3][3] += a.w * b.w;
        }
        __syncthreads();
    }

    float4 bv = make_float4(0.f, 0.f, 0.f, 0.f);
    if (BIAS) bv = *reinterpret_cast<const float4*>(&bias[n0 + tx * 4]);
    #pragma unroll
    for (int i = 0; i < 4; ++i) {
        int gm = m0 + ty * 4 + i;
        if (gm >= M) break;
        float4 o;
        o.x = acc[i][0] + bv.x; o.y = acc[i][1] + bv.y;
        o.z = acc[i][2] + bv.z; o.w = acc[i][3] + bv.w;
        if (RELU) {
            o.x = fmaxf(o.x, 0.f); o.y = fmaxf(o.y, 0.f);
            o.z = fmaxf(o.z, 0.f); o.w = fmaxf(o.w, 0.f);
        }
        *reinterpret_cast<float4*>(&C[(size_t)gm * N + n0 + tx * 4]) = o;
    }
}

extern "C" void kernel_launch(void* const* d_in, const int* in_sizes, int n_in,
                              void* d_out, int out_size, void* d_ws, size_t ws_size,
                              hipStream_t stream) {
    const float* x  = (const float*)d_in[0];
    const int*   ei = (const int*)d_in[1];
    const float* W1 = (const float*)d_in[2];
    const float* b1 = (const float*)d_in[3];
    const float* W2 = (const float*)d_in[4];
    const float* b2 = (const float*)d_in[5];
    float* out = (float*)d_out;

    const int N = NNODES;
    const int E = in_sizes[1] / 2;
    const int IN_D = 128, HID = 256;
    const int* row = ei;
    const int* col = ei + E;

    // workspace carve-out (aligned to 256B)
    char* ws = (char*)d_ws;
    size_t off = 0;
    auto carve = [&](size_t bytes) { void* p = ws + off; off += (bytes + 255) & ~size_t(255); return p; };
    int*   cnt     = (int*)carve((size_t)N * 4);
    int*   row_ptr = (int*)carve((size_t)(N + 1) * 4);
    int*   cursor  = (int*)carve((size_t)N * 4);
    float* dinv    = (float*)carve((size_t)N * 4);
    int*   cols    = (int*)carve((size_t)E * 4);
    float* y1      = (float*)carve((size_t)N * IN_D * 4);   // reused as z
    float* h       = (float*)carve((size_t)N * HID * 4);
    float* z = y1;

    const int TB = 256;
    // 1) CSR build: count -> scan -> scatter ; dinv from counts
    cnt_init<<<(N + TB - 1) / TB, TB, 0, stream>>>(cnt, N);
    deg_count<<<(E + TB - 1) / TB, TB, 0, stream>>>(row, cnt, E);
    calc_dinv<<<(N + TB - 1) / TB, TB, 0, stream>>>(cnt, dinv, N);
    scan_kernel<<<1, 1024, 0, stream>>>(cnt, row_ptr, cursor, N);
    scatter_edges<<<(E + TB - 1) / TB, TB, 0, stream>>>(row, col, cursor, cols, E);

    // 2) y1 = A' x
    spmm_csr<<<(N * 32 + TB - 1) / TB, TB, 0, stream>>>(row_ptr, cols, dinv, x, nullptr, y1, N);

    // 3) h = relu(y1 @ W1^T + b1)   [N,128] -> [N,256]
    {
        dim3 grid(HID / 64, (N + 63) / 64);
        gemm_nt<true, true><<<grid, 256, 0, stream>>>(y1, W1, b1, h, N, HID, IN_D);
    }

    // 4) z = h @ W2^T               [N,256] -> [N,128]   (b2 deferred past SPMM2)
    {
        dim3 grid(IN_D / 64, (N + 63) / 64);
        gemm_nt<false, false><<<grid, 256, 0, stream>>>(h, W2, nullptr, z, N, IN_D, HID);
    }

    // 5) out = A' z + b2
    spmm_csr<<<(N * 32 + TB - 1) / TB, TB, 0, stream>>>(row_ptr, cols, dinv, z, b2, out, N);
}

// Round 3
// 341.503 us; speedup vs baseline: 8.3927x; 1.2894x over previous
//
#include <hip/hip_runtime.h>
#include <hip/hip_bf16.h>

#define NNODES 50000
#define DIM 128   // both SPMMs run on 128 dims after the W2 reorder
#define SCAN_CHUNK 2048   // 256 threads * 8 elements

// ---------------- degree count ----------------
__global__ void cnt_init(int* __restrict__ cnt, int n) {
    int i = blockIdx.x * blockDim.x + threadIdx.x;
    if (i < n) cnt[i] = 0;
}

__global__ void deg_count(const int* __restrict__ row, int* __restrict__ cnt, int nE) {
    int e = blockIdx.x * blockDim.x + threadIdx.x;
    if (e < nE) atomicAdd(&cnt[row[e]], 1);
}

// ---------------- multi-block exclusive scan ----------------
// A: per-block sums of SCAN_CHUNK-element chunks
__global__ __launch_bounds__(256) void block_sums(const int* __restrict__ cnt,
                                                  int* __restrict__ bsum, int n) {
    __shared__ int red[256];
    int b = blockIdx.x, t = threadIdx.x;
    int base = b * SCAN_CHUNK + t * 8;
    int s = 0;
    #pragma unroll
    for (int k = 0; k < 8; ++k) { int i = base + k; if (i < n) s += cnt[i]; }
    red[t] = s;
    __syncthreads();
    for (int off = 128; off > 0; off >>= 1) {
        if (t < off) red[t] += red[t + off];
        __syncthreads();
    }
    if (t == 0) bsum[b] = red[0];
}

// B: each block computes its global offset from bsum[], scans its chunk,
//    writes row_ptr + cursor; also emits dinv (reads cnt anyway).
__global__ __launch_bounds__(256) void scan_write(const int* __restrict__ cnt,
                                                  const int* __restrict__ bsum, int nblocks,
                                                  int* __restrict__ row_ptr, int* __restrict__ cursor,
                                                  float* __restrict__ dinv, int n) {
    __shared__ int ssum[256];
    int b = blockIdx.x, t = threadIdx.x;
    int boff = 0, total = 0;
    for (int k = 0; k < nblocks; ++k) { int v = bsum[k]; boff += (k < b) ? v : 0; total += v; }
    int base = b * SCAN_CHUNK + t * 8;
    int local[8]; int s = 0;
    #pragma unroll
    for (int k = 0; k < 8; ++k) { int i = base + k; local[k] = (i < n) ? cnt[i] : 0; s += local[k]; }
    ssum[t] = s;
    __syncthreads();
    for (int off = 1; off < 256; off <<= 1) {
        int v = (t >= off) ? ssum[t - off] : 0;
        __syncthreads();
        ssum[t] += v;
        __syncthreads();
    }
    int run = boff + ((t == 0) ? 0 : ssum[t - 1]);
    #pragma unroll
    for (int k = 0; k < 8; ++k) {
        int i = base + k;
        if (i < n) {
            row_ptr[i] = run;
            cursor[i]  = run;
            dinv[i] = rsqrtf((float)(local[k] + 1));   // +1 self loop; deg>=1 so clip no-op
            run += local[k];
        }
    }
    if (b == 0 && t == 0) row_ptr[n] = total;
}

// ---------------- scatter edges into CSR ----------------
__global__ void scatter_edges(const int* __restrict__ row, const int* __restrict__ col,
                              int* __restrict__ cursor, int* __restrict__ cols, int nE) {
    int e = blockIdx.x * blockDim.x + threadIdx.x;
    if (e < nE) {
        int pos = atomicAdd(&cursor[row[e]], 1);
        cols[pos] = col[e];
    }
}

// ---------------- CSR SPMM (gather, no fp atomics) ----------------
// Y[i,:] = dinv[i] * ( dinv[i]*X[i,:] + sum_j dinv[c_j]*X[c_j,:] ) (+ bias)
__global__ __launch_bounds__(256) void spmm_csr(const int* __restrict__ row_ptr,
                         const int* __restrict__ cols, const float* __restrict__ dinv,
                         const float* __restrict__ X, const float* __restrict__ bias,
                         float* __restrict__ Y, int n) {
    int tid = blockIdx.x * blockDim.x + threadIdx.x;
    int i = tid >> 5;        // node
    int l = tid & 31;        // float4 slot (DIM/4 == 32)
    if (i >= n) return;
    const float4* X4 = reinterpret_cast<const float4*>(X);
    float di = dinv[i];
    float4 xv = X4[(size_t)i * 32 + l];
    float4 acc;
    acc.x = di * xv.x; acc.y = di * xv.y; acc.z = di * xv.z; acc.w = di * xv.w;
    int s = row_ptr[i], e = row_ptr[i + 1];
    int j = s;
    for (; j + 1 < e; j += 2) {
        int c0 = cols[j], c1 = cols[j + 1];
        float w0 = dinv[c0], w1 = dinv[c1];
        float4 v0 = X4[(size_t)c0 * 32 + l];
        float4 v1 = X4[(size_t)c1 * 32 + l];
        acc.x += w0 * v0.x + w1 * v1.x;
        acc.y += w0 * v0.y + w1 * v1.y;
        acc.z += w0 * v0.z + w1 * v1.z;
        acc.w += w0 * v0.w + w1 * v1.w;
    }
    if (j < e) {
        int c0 = cols[j];
        float w0 = dinv[c0];
        float4 v0 = X4[(size_t)c0 * 32 + l];
        acc.x += w0 * v0.x; acc.y += w0 * v0.y;
        acc.z += w0 * v0.z; acc.w += w0 * v0.w;
    }
    acc.x *= di; acc.y *= di; acc.z *= di; acc.w *= di;
    if (bias) {
        float4 b = reinterpret_cast<const float4*>(bias)[l];
        acc.x += b.x; acc.y += b.y; acc.z += b.z; acc.w += b.w;
    }
    reinterpret_cast<float4*>(Y)[(size_t)i * 32 + l] = acc;
}

// ---------------- GEMM (NT): C[m,n] = sum_k A[m,k]*B[n,k] (+bias[n]) (relu) ----------------
template <bool RELU, bool BIAS>
__global__ __launch_bounds__(256) void gemm_nt(const float* __restrict__ A, const float* __restrict__ B,
                        const float* __restrict__ bias, float* __restrict__ C,
                        int M, int N, int K) {
    constexpr int BM = 64, BN = 64, BK = 16;
    __shared__ float As[BK][BM + 4];
    __shared__ float Bs[BK][BN + 4];
    int m0 = blockIdx.y * BM, n0 = blockIdx.x * BN;
    int tid = threadIdx.x;          // 256 threads
    int tx = tid & 15, ty = tid >> 4;
    float acc[4][4] = {};

    for (int k0 = 0; k0 < K; k0 += BK) {
        {
            int r = tid >> 2;          // 0..63
            int q = tid & 3;           // 0..3  (k quad)
            int gm = m0 + r;
            float4 v = make_float4(0.f, 0.f, 0.f, 0.f);
            if (gm < M) v = *reinterpret_cast<const float4*>(&A[(size_t)gm * K + k0 + q * 4]);
            As[q * 4 + 0][r] = v.x; As[q * 4 + 1][r] = v.y;
            As[q * 4 + 2][r] = v.z; As[q * 4 + 3][r] = v.w;
            float4 w = *reinterpret_cast<const float4*>(&B[(size_t)(n0 + r) * K + k0 + q * 4]);
            Bs[q * 4 + 0][r] = w.x; Bs[q * 4 + 1][r] = w.y;
            Bs[q * 4 + 2][r] = w.z; Bs[q * 4 + 3][r] = w.w;
        }
        __syncthreads();
        #pragma unroll
        for (int kk = 0; kk < BK; ++kk) {
            float4 a = *reinterpret_cast<const float4*>(&As[kk][ty * 4]);
            float4 b = *reinterpret_cast<const float4*>(&Bs[kk][tx * 4]);
            acc[0][0] += a.x * b.x; acc[0][1] += a.x * b.y; acc[0][2] += a.x * b.z; acc[0][3] += a.x * b.w;
            acc[1][0] += a.y * b.x; acc[1][1] += a.y * b.y; acc[1][2] += a.y * b.z; acc[1][3] += a.y * b.w;
            acc[2][0] += a.z * b.x; acc[2][1] += a.z * b.y; acc[2][2] += a.z * b.z; acc[2][3] += a.z * b.w;
            acc[3][0] += a.w * b.x; acc[3][1] += a.w * b.y; acc[3][2] += a.w * b.z; acc[3][3] += a.w * b.w;
        }
        __syncthreads();
    }

    float4 bv = make_float4(0.f, 0.f, 0.f, 0.f);
    if (BIAS) bv = *reinterpret_cast<const float4*>(&bias[n0 + tx * 4]);
    #pragma unroll
    for (int i = 0; i < 4; ++i) {
        int gm = m0 + ty * 4 + i;
        if (gm >= M) break;
        float4 o;
        o.x = acc[i][0] + bv.x; o.y = acc[i][1] + bv.y;
        o.z = acc[i][2] + bv.z; o.w = acc[i][3] + bv.w;
        if (RELU) {
            o.x = fmaxf(o.x, 0.f); o.y = fmaxf(o.y, 0.f);
            o.z = fmaxf(o.z, 0.f); o.w = fmaxf(o.w, 0.f);
        }
        *reinterpret_cast<float4*>(&C[(size_t)gm * N + n0 + tx * 4]) = o;
    }
}

extern "C" void kernel_launch(void* const* d_in, const int* in_sizes, int n_in,
                              void* d_out, int out_size, void* d_ws, size_t ws_size,
                              hipStream_t stream) {
    const float* x  = (const float*)d_in[0];
    const int*   ei = (const int*)d_in[1];
    const float* W1 = (const float*)d_in[2];
    const float* b1 = (const float*)d_in[3];
    const float* W2 = (const float*)d_in[4];
    const float* b2 = (const float*)d_in[5];
    float* out = (float*)d_out;

    const int N = NNODES;
    const int E = in_sizes[1] / 2;
    const int IN_D = 128, HID = 256;
    const int* row = ei;
    const int* col = ei + E;

    // workspace carve-out (aligned to 256B)
    char* ws = (char*)d_ws;
    size_t off = 0;
    auto carve = [&](size_t bytes) { void* p = ws + off; off += (bytes + 255) & ~size_t(255); return p; };
    int*   cnt     = (int*)carve((size_t)N * 4);
    int*   row_ptr = (int*)carve((size_t)(N + 1) * 4);
    int*   cursor  = (int*)carve((size_t)N * 4);
    float* dinv    = (float*)carve((size_t)N * 4);
    int*   bsum    = (int*)carve((size_t)64 * 4);
    int*   cols    = (int*)carve((size_t)E * 4);
    float* y1      = (float*)carve((size_t)N * IN_D * 4);   // reused as z
    float* h       = (float*)carve((size_t)N * HID * 4);
    float* z = y1;

    const int TB = 256;
    const int nscan = (N + SCAN_CHUNK - 1) / SCAN_CHUNK;   // 25
    // 1) CSR build: count -> 2-kernel scan (emits dinv too) -> scatter
    cnt_init<<<(N + TB - 1) / TB, TB, 0, stream>>>(cnt, N);
    deg_count<<<(E + TB - 1) / TB, TB, 0, stream>>>(row, cnt, E);
    block_sums<<<nscan, TB, 0, stream>>>(cnt, bsum, N);
    scan_write<<<nscan, TB, 0, stream>>>(cnt, bsum, nscan, row_ptr, cursor, dinv, N);
    scatter_edges<<<(E + TB - 1) / TB, TB, 0, stream>>>(row, col, cursor, cols, E);

    // 2) y1 = A' x
    spmm_csr<<<(N * 32 + TB - 1) / TB, TB, 0, stream>>>(row_ptr, cols, dinv, x, nullptr, y1, N);

    // 3) h = relu(y1 @ W1^T + b1)   [N,128] -> [N,256]
    {
        dim3 grid(HID / 64, (N + 63) / 64);
        gemm_nt<true, true><<<grid, 256, 0, stream>>>(y1, W1, b1, h, N, HID, IN_D);
    }

    // 4) z = h @ W2^T               [N,256] -> [N,128]   (b2 deferred past SPMM2)
    {
        dim3 grid(IN_D / 64, (N + 63) / 64);
        gemm_nt<false, false><<<grid, 256, 0, stream>>>(h, W2, nullptr, z, N, IN_D, HID);
    }

    // 5) out = A' z + b2
    spmm_csr<<<(N * 32 + TB - 1) / TB, TB, 0, stream>>>(row_ptr, cols, dinv, z, b2, out, N);
}

// Round 4
// 325.645 us; speedup vs baseline: 8.8014x; 1.0487x over previous
//
#include <hip/hip_runtime.h>
#include <hip/hip_bf16.h>

#define NNODES 50000
#define DIM 128   // both SPMMs run on 128 dims after the W2 reorder
#define SCAN_CHUNK 2048   // 256 threads * 8 elements

typedef unsigned short u16;
typedef short  bf16x8 __attribute__((ext_vector_type(8)));
typedef float  f32x4  __attribute__((ext_vector_type(4)));

#define MFMA16(a, b, c) __builtin_amdgcn_mfma_f32_16x16x32_bf16((a), (b), (c), 0, 0, 0)

// ---------------- bf16 split helpers ----------------
__device__ __forceinline__ u16 bf16_rne(float f) {
    unsigned u = __builtin_bit_cast(unsigned, f);
    u += 0x7fffu + ((u >> 16) & 1u);
    return (u16)(u >> 16);
}
__device__ __forceinline__ void split2(float f, u16& hi, u16& lo) {
    u16 h = bf16_rne(f);
    float hf = __builtin_bit_cast(float, (unsigned)h << 16);
    hi = h;
    lo = bf16_rne(f - hf);
}
__device__ __forceinline__ bf16x8 ldfrag(const u16* p) {
    return *reinterpret_cast<const bf16x8*>(p);
}

// ---------------- degree count ----------------
__global__ void cnt_init(int* __restrict__ cnt, int n) {
    int i = blockIdx.x * blockDim.x + threadIdx.x;
    if (i < n) cnt[i] = 0;
}

__global__ void deg_count(const int* __restrict__ row, int* __restrict__ cnt, int nE) {
    int e = blockIdx.x * blockDim.x + threadIdx.x;
    if (e < nE) atomicAdd(&cnt[row[e]], 1);
}

// ---------------- weight split fp32 -> (hi, lo) bf16 ----------------
__global__ void split_f32(const float* __restrict__ w, u16* __restrict__ hi,
                          u16* __restrict__ lo, int n) {
    int i = blockIdx.x * blockDim.x + threadIdx.x;
    if (i < n) { u16 h, l; split2(w[i], h, l); hi[i] = h; lo[i] = l; }
}

// ---------------- multi-block exclusive scan ----------------
__global__ __launch_bounds__(256) void block_sums(const int* __restrict__ cnt,
                                                  int* __restrict__ bsum, int n) {
    __shared__ int red[256];
    int b = blockIdx.x, t = threadIdx.x;
    int base = b * SCAN_CHUNK + t * 8;
    int s = 0;
    #pragma unroll
    for (int k = 0; k < 8; ++k) { int i = base + k; if (i < n) s += cnt[i]; }
    red[t] = s;
    __syncthreads();
    for (int off = 128; off > 0; off >>= 1) {
        if (t < off) red[t] += red[t + off];
        __syncthreads();
    }
    if (t == 0) bsum[b] = red[0];
}

__global__ __launch_bounds__(256) void scan_write(const int* __restrict__ cnt,
                                                  const int* __restrict__ bsum, int nblocks,
                                                  int* __restrict__ row_ptr, int* __restrict__ cursor,
                                                  float* __restrict__ dinv, int n) {
    __shared__ int ssum[256];
    int b = blockIdx.x, t = threadIdx.x;
    int boff = 0, total = 0;
    for (int k = 0; k < nblocks; ++k) { int v = bsum[k]; boff += (k < b) ? v : 0; total += v; }
    int base = b * SCAN_CHUNK + t * 8;
    int local[8]; int s = 0;
    #pragma unroll
    for (int k = 0; k < 8; ++k) { int i = base + k; local[k] = (i < n) ? cnt[i] : 0; s += local[k]; }
    ssum[t] = s;
    __syncthreads();
    for (int off = 1; off < 256; off <<= 1) {
        int v = (t >= off) ? ssum[t - off] : 0;
        __syncthreads();
        ssum[t] += v;
        __syncthreads();
    }
    int run = boff + ((t == 0) ? 0 : ssum[t - 1]);
    #pragma unroll
    for (int k = 0; k < 8; ++k) {
        int i = base + k;
        if (i < n) {
            row_ptr[i] = run;
            cursor[i]  = run;
            dinv[i] = rsqrtf((float)(local[k] + 1));
            run += local[k];
        }
    }
    if (b == 0 && t == 0) row_ptr[n] = total;
}

// ---------------- scatter edges into CSR ----------------
__global__ void scatter_edges(const int* __restrict__ row, const int* __restrict__ col,
                              int* __restrict__ cursor, int* __restrict__ cols, int nE) {
    int e = blockIdx.x * blockDim.x + threadIdx.x;
    if (e < nE) {
        int pos = atomicAdd(&cursor[row[e]], 1);
        cols[pos] = col[e];
    }
}

// ---------------- CSR SPMM (gather, no fp atomics) ----------------
// Y[i,:] = dinv[i] * ( dinv[i]*X[i,:] + sum_j dinv[c_j]*X[c_j,:] ) (+ bias)
// SPLIT_OUT: emit (hi, lo) bf16 pair instead of fp32.
template <bool SPLIT_OUT, bool BIAS>
__global__ __launch_bounds__(256) void spmm_csr(const int* __restrict__ row_ptr,
                         const int* __restrict__ cols, const float* __restrict__ dinv,
                         const float* __restrict__ X, const float* __restrict__ bias,
                         float* __restrict__ Y, u16* __restrict__ Yhi, u16* __restrict__ Ylo,
                         int n) {
    int tid = blockIdx.x * blockDim.x + threadIdx.x;
    int i = tid >> 5;        // node
    int l = tid & 31;        // float4 slot (DIM/4 == 32)
    if (i >= n) return;
    const float4* X4 = reinterpret_cast<const float4*>(X);
    float di = dinv[i];
    float4 xv = X4[(size_t)i * 32 + l];
    float4 acc;
    acc.x = di * xv.x; acc.y = di * xv.y; acc.z = di * xv.z; acc.w = di * xv.w;
    int s = row_ptr[i], e = row_ptr[i + 1];
    int j = s;
    for (; j + 1 < e; j += 2) {
        int c0 = cols[j], c1 = cols[j + 1];
        float w0 = dinv[c0], w1 = dinv[c1];
        float4 v0 = X4[(size_t)c0 * 32 + l];
        float4 v1 = X4[(size_t)c1 * 32 + l];
        acc.x += w0 * v0.x + w1 * v1.x;
        acc.y += w0 * v0.y + w1 * v1.y;
        acc.z += w0 * v0.z + w1 * v1.z;
        acc.w += w0 * v0.w + w1 * v1.w;
    }
    if (j < e) {
        int c0 = cols[j];
        float w0 = dinv[c0];
        float4 v0 = X4[(size_t)c0 * 32 + l];
        acc.x += w0 * v0.x; acc.y += w0 * v0.y;
        acc.z += w0 * v0.z; acc.w += w0 * v0.w;
    }
    acc.x *= di; acc.y *= di; acc.z *= di; acc.w *= di;
    if (BIAS) {
        float4 b = reinterpret_cast<const float4*>(bias)[l];
        acc.x += b.x; acc.y += b.y; acc.z += b.z; acc.w += b.w;
    }
    if (SPLIT_OUT) {
        ushort4 hv, lv;
        split2(acc.x, hv.x, lv.x); split2(acc.y, hv.y, lv.y);
        split2(acc.z, hv.z, lv.z); split2(acc.w, hv.w, lv.w);
        *reinterpret_cast<ushort4*>(&Yhi[(size_t)i * DIM + l * 4]) = hv;
        *reinterpret_cast<ushort4*>(&Ylo[(size_t)i * DIM + l * 4]) = lv;
    } else {
        reinterpret_cast<float4*>(Y)[(size_t)i * 32 + l] = acc;
    }
}

// ---------------- MFMA split-bf16 GEMM (NT): C[m,n] = sum_k A[m,k]*B[n,k] ----------------
// a*b ~= ah*bh + ah*bl + al*bh  (fp32 accumulate).  No LDS, no barriers:
// each wave owns a 32x64 tile; frags loaded straight from global (A rows hot in
// L1/L2, W split is 128KB -> L2-resident for all blocks).
template <int K, bool RELU, bool BIAS, bool SPLIT_OUT>
__global__ __launch_bounds__(256) void gemm_mfma(
        const u16* __restrict__ Ahi, const u16* __restrict__ Alo,
        const u16* __restrict__ Bhi, const u16* __restrict__ Blo,
        const float* __restrict__ bias, float* __restrict__ C,
        u16* __restrict__ Chi, u16* __restrict__ Clo, int M, int N) {
    const int wave = threadIdx.x >> 6;
    const int lane = threadIdx.x & 63;
    const int lr = lane & 15;   // fragment row/col
    const int lq = lane >> 4;   // k-quad (8 elems each)
    const int m0 = blockIdx.y * 128 + wave * 32;
    const int n0 = blockIdx.x * 64;

    f32x4 acc[2][4] = {};

    // clamp A row indices (rows >= M accumulate junk but are never stored)
    const int ar0 = min(m0 + lr,      M - 1);
    const int ar1 = min(m0 + 16 + lr, M - 1);
    const u16* pa0h = Ahi + (size_t)ar0 * K + lq * 8;
    const u16* pa0l = Alo + (size_t)ar0 * K + lq * 8;
    const u16* pa1h = Ahi + (size_t)ar1 * K + lq * 8;
    const u16* pa1l = Alo + (size_t)ar1 * K + lq * 8;
    const u16* pbh  = Bhi + (size_t)(n0 + lr) * K + lq * 8;
    const u16* pbl  = Blo + (size_t)(n0 + lr) * K + lq * 8;

    #pragma unroll 2
    for (int k0 = 0; k0 < K; k0 += 32) {
        bf16x8 a0h = ldfrag(pa0h + k0), a0l = ldfrag(pa0l + k0);
        bf16x8 a1h = ldfrag(pa1h + k0), a1l = ldfrag(pa1l + k0);
        bf16x8 bh[4], bl[4];
        #pragma unroll
        for (int nf = 0; nf < 4; ++nf) {
            bh[nf] = ldfrag(pbh + (size_t)nf * 16 * K + k0);
            bl[nf] = ldfrag(pbl + (size_t)nf * 16 * K + k0);
        }
        #pragma unroll
        for (int nf = 0; nf < 4; ++nf) {
            acc[0][nf] = MFMA16(a0h, bh[nf], acc[0][nf]);
            acc[0][nf] = MFMA16(a0h, bl[nf], acc[0][nf]);
            acc[0][nf] = MFMA16(a0l, bh[nf], acc[0][nf]);
            acc[1][nf] = MFMA16(a1h, bh[nf], acc[1][nf]);
            acc[1][nf] = MFMA16(a1h, bl[nf], acc[1][nf]);
            acc[1][nf] = MFMA16(a1l, bh[nf], acc[1][nf]);
        }
    }

    // epilogue: C/D layout col = lane&15 (n), row = (lane>>4)*4 + i (m)
    #pragma unroll
    for (int mf = 0; mf < 2; ++mf) {
        #pragma unroll
        for (int i = 0; i < 4; ++i) {
            int m = m0 + mf * 16 + lq * 4 + i;
            if (m >= M) continue;
            #pragma unroll
            for (int nf = 0; nf < 4; ++nf) {
                int n = n0 + nf * 16 + lr;
                float v = acc[mf][nf][i];
                if (BIAS) v += bias[n];
                if (RELU) v = fmaxf(v, 0.f);
                if (SPLIT_OUT) {
                    u16 h, l; split2(v, h, l);
                    Chi[(size_t)m * N + n] = h;
                    Clo[(size_t)m * N + n] = l;
                } else {
                    C[(size_t)m * N + n] = v;
                }
            }
        }
    }
}

extern "C" void kernel_launch(void* const* d_in, const int* in_sizes, int n_in,
                              void* d_out, int out_size, void* d_ws, size_t ws_size,
                              hipStream_t stream) {
    const float* x  = (const float*)d_in[0];
    const int*   ei = (const int*)d_in[1];
    const float* W1 = (const float*)d_in[2];
    const float* b1 = (const float*)d_in[3];
    const float* W2 = (const float*)d_in[4];
    const float* b2 = (const float*)d_in[5];
    float* out = (float*)d_out;

    const int N = NNODES;
    const int E = in_sizes[1] / 2;
    const int IN_D = 128, HID = 256;
    const int* row = ei;
    const int* col = ei + E;

    // workspace carve-out (aligned to 256B)
    char* ws = (char*)d_ws;
    size_t off = 0;
    auto carve = [&](size_t bytes) { void* p = ws + off; off += (bytes + 255) & ~size_t(255); return p; };
    int*   cnt     = (int*)carve((size_t)N * 4);
    int*   row_ptr = (int*)carve((size_t)(N + 1) * 4);
    int*   cursor  = (int*)carve((size_t)N * 4);
    float* dinv    = (float*)carve((size_t)N * 4);
    int*   bsum    = (int*)carve((size_t)64 * 4);
    int*   cols    = (int*)carve((size_t)E * 4);
    u16*   w1hi    = (u16*)carve((size_t)HID * IN_D * 2);
    u16*   w1lo    = (u16*)carve((size_t)HID * IN_D * 2);
    u16*   w2hi    = (u16*)carve((size_t)IN_D * HID * 2);
    u16*   w2lo    = (u16*)carve((size_t)IN_D * HID * 2);
    u16*   y1hi    = (u16*)carve((size_t)N * IN_D * 2);   // 12.8 MB
    u16*   y1lo    = (u16*)carve((size_t)N * IN_D * 2);   // 12.8 MB
    u16*   hhi     = (u16*)carve((size_t)N * HID * 2);    // 25.6 MB
    u16*   hlo     = (u16*)carve((size_t)N * HID * 2);    // 25.6 MB
    float* z       = (float*)y1hi;   // y1 split is dead after GEMM1; reuse 25.6MB for z

    const int TB = 256;
    const int nscan = (N + SCAN_CHUNK - 1) / SCAN_CHUNK;   // 25
    // 1) CSR build: count -> 2-kernel scan (emits dinv too) -> scatter; weight splits
    cnt_init<<<(N + TB - 1) / TB, TB, 0, stream>>>(cnt, N);
    deg_count<<<(E + TB - 1) / TB, TB, 0, stream>>>(row, cnt, E);
    block_sums<<<nscan, TB, 0, stream>>>(cnt, bsum, N);
    scan_write<<<nscan, TB, 0, stream>>>(cnt, bsum, nscan, row_ptr, cursor, dinv, N);
    scatter_edges<<<(E + TB - 1) / TB, TB, 0, stream>>>(row, col, cursor, cols, E);
    split_f32<<<(HID * IN_D + TB - 1) / TB, TB, 0, stream>>>(W1, w1hi, w1lo, HID * IN_D);
    split_f32<<<(IN_D * HID + TB - 1) / TB, TB, 0, stream>>>(W2, w2hi, w2lo, IN_D * HID);

    // 2) y1 = A' x   (emitted as split bf16 for GEMM1)
    spmm_csr<true, false><<<(N * 32 + TB - 1) / TB, TB, 0, stream>>>(
        row_ptr, cols, dinv, x, nullptr, nullptr, y1hi, y1lo, N);

    // 3) h = relu(y1 @ W1^T + b1)   [N,128] -> [N,256], split output
    {
        dim3 grid(HID / 64, (N + 127) / 128);
        gemm_mfma<128, true, true, true><<<grid, 256, 0, stream>>>(
            y1hi, y1lo, w1hi, w1lo, b1, nullptr, hhi, hlo, N, HID);
    }

    // 4) z = h @ W2^T               [N,256] -> [N,128] fp32 (b2 deferred past SPMM2)
    {
        dim3 grid(IN_D / 64, (N + 127) / 128);
        gemm_mfma<256, false, false, false><<<grid, 256, 0, stream>>>(
            hhi, hlo, w2hi, w2lo, nullptr, z, nullptr, nullptr, N, IN_D);
    }

    // 5) out = A' z + b2
    spmm_csr<false, true><<<(N * 32 + TB - 1) / TB, TB, 0, stream>>>(
        row_ptr, cols, dinv, z, b2, out, nullptr, nullptr, N);
}

// Round 5
// 319.487 us; speedup vs baseline: 8.9711x; 1.0193x over previous
//
#include <hip/hip_runtime.h>
#include <hip/hip_bf16.h>

#define NNODES 50000
#define DIM 128   // both SPMMs run on 128 dims after the W2 reorder
#define SCAN_CHUNK 2048   // 256 threads * 8 elements

typedef unsigned short u16;
typedef short  bf16x8 __attribute__((ext_vector_type(8)));
typedef float  f32x4  __attribute__((ext_vector_type(4)));

#define MFMA16(a, b, c) __builtin_amdgcn_mfma_f32_16x16x32_bf16((a), (b), (c), 0, 0, 0)

// ---------------- bf16 split helpers ----------------
__device__ __forceinline__ u16 bf16_rne(float f) {
    unsigned u = __builtin_bit_cast(unsigned, f);
    u += 0x7fffu + ((u >> 16) & 1u);
    return (u16)(u >> 16);
}
__device__ __forceinline__ void split2(float f, u16& hi, u16& lo) {
    u16 h = bf16_rne(f);
    float hf = __builtin_bit_cast(float, (unsigned)h << 16);
    hi = h;
    lo = bf16_rne(f - hf);
}
__device__ __forceinline__ bf16x8 ldfrag(const u16* p) {
    return *reinterpret_cast<const bf16x8*>(p);
}

// ---------------- degree count ----------------
__global__ void cnt_init(int* __restrict__ cnt, int n) {
    int i = blockIdx.x * blockDim.x + threadIdx.x;
    if (i < n) cnt[i] = 0;
}

__global__ void deg_count(const int* __restrict__ row, int* __restrict__ cnt, int nE) {
    int e = blockIdx.x * blockDim.x + threadIdx.x;
    if (e < nE) atomicAdd(&cnt[row[e]], 1);
}

// ---------------- weight split fp32 -> (hi, lo) bf16 ----------------
__global__ void split_f32(const float* __restrict__ w, u16* __restrict__ hi,
                          u16* __restrict__ lo, int n) {
    int i = blockIdx.x * blockDim.x + threadIdx.x;
    if (i < n) { u16 h, l; split2(w[i], h, l); hi[i] = h; lo[i] = l; }
}

// ---------------- multi-block exclusive scan ----------------
__global__ __launch_bounds__(256) void block_sums(const int* __restrict__ cnt,
                                                  int* __restrict__ bsum, int n) {
    __shared__ int red[256];
    int b = blockIdx.x, t = threadIdx.x;
    int base = b * SCAN_CHUNK + t * 8;
    int s = 0;
    #pragma unroll
    for (int k = 0; k < 8; ++k) { int i = base + k; if (i < n) s += cnt[i]; }
    red[t] = s;
    __syncthreads();
    for (int off = 128; off > 0; off >>= 1) {
        if (t < off) red[t] += red[t + off];
        __syncthreads();
    }
    if (t == 0) bsum[b] = red[0];
}

__global__ __launch_bounds__(256) void scan_write(const int* __restrict__ cnt,
                                                  const int* __restrict__ bsum, int nblocks,
                                                  int* __restrict__ row_ptr, int* __restrict__ cursor,
                                                  float* __restrict__ dinv, int n) {
    __shared__ int ssum[256];
    int b = blockIdx.x, t = threadIdx.x;
    int boff = 0, total = 0;
    for (int k = 0; k < nblocks; ++k) { int v = bsum[k]; boff += (k < b) ? v : 0; total += v; }
    int base = b * SCAN_CHUNK + t * 8;
    int local[8]; int s = 0;
    #pragma unroll
    for (int k = 0; k < 8; ++k) { int i = base + k; local[k] = (i < n) ? cnt[i] : 0; s += local[k]; }
    ssum[t] = s;
    __syncthreads();
    for (int off = 1; off < 256; off <<= 1) {
        int v = (t >= off) ? ssum[t - off] : 0;
        __syncthreads();
        ssum[t] += v;
        __syncthreads();
    }
    int run = boff + ((t == 0) ? 0 : ssum[t - 1]);
    #pragma unroll
    for (int k = 0; k < 8; ++k) {
        int i = base + k;
        if (i < n) {
            row_ptr[i] = run;
            cursor[i]  = run;
            dinv[i] = rsqrtf((float)(local[k] + 1));
            run += local[k];
        }
    }
    if (b == 0 && t == 0) row_ptr[n] = total;
}

// ---------------- scatter edges into CSR ----------------
__global__ void scatter_edges(const int* __restrict__ row, const int* __restrict__ col,
                              int* __restrict__ cursor, int* __restrict__ cols, int nE) {
    int e = blockIdx.x * blockDim.x + threadIdx.x;
    if (e < nE) {
        int pos = atomicAdd(&cursor[row[e]], 1);
        cols[pos] = col[e];
    }
}

// ---------------- CSR SPMM (gather, no fp atomics) ----------------
template <bool SPLIT_OUT, bool BIAS>
__global__ __launch_bounds__(256) void spmm_csr(const int* __restrict__ row_ptr,
                         const int* __restrict__ cols, const float* __restrict__ dinv,
                         const float* __restrict__ X, const float* __restrict__ bias,
                         float* __restrict__ Y, u16* __restrict__ Yhi, u16* __restrict__ Ylo,
                         int n) {
    int tid = blockIdx.x * blockDim.x + threadIdx.x;
    int i = tid >> 5;        // node
    int l = tid & 31;        // float4 slot (DIM/4 == 32)
    if (i >= n) return;
    const float4* X4 = reinterpret_cast<const float4*>(X);
    float di = dinv[i];
    float4 xv = X4[(size_t)i * 32 + l];
    float4 acc;
    acc.x = di * xv.x; acc.y = di * xv.y; acc.z = di * xv.z; acc.w = di * xv.w;
    int s = row_ptr[i], e = row_ptr[i + 1];
    int j = s;
    for (; j + 1 < e; j += 2) {
        int c0 = cols[j], c1 = cols[j + 1];
        float w0 = dinv[c0], w1 = dinv[c1];
        float4 v0 = X4[(size_t)c0 * 32 + l];
        float4 v1 = X4[(size_t)c1 * 32 + l];
        acc.x += w0 * v0.x + w1 * v1.x;
        acc.y += w0 * v0.y + w1 * v1.y;
        acc.z += w0 * v0.z + w1 * v1.z;
        acc.w += w0 * v0.w + w1 * v1.w;
    }
    if (j < e) {
        int c0 = cols[j];
        float w0 = dinv[c0];
        float4 v0 = X4[(size_t)c0 * 32 + l];
        acc.x += w0 * v0.x; acc.y += w0 * v0.y;
        acc.z += w0 * v0.z; acc.w += w0 * v0.w;
    }
    acc.x *= di; acc.y *= di; acc.z *= di; acc.w *= di;
    if (BIAS) {
        float4 b = reinterpret_cast<const float4*>(bias)[l];
        acc.x += b.x; acc.y += b.y; acc.z += b.z; acc.w += b.w;
    }
    if (SPLIT_OUT) {
        ushort4 hv, lv;
        split2(acc.x, hv.x, lv.x); split2(acc.y, hv.y, lv.y);
        split2(acc.z, hv.z, lv.z); split2(acc.w, hv.w, lv.w);
        *reinterpret_cast<ushort4*>(&Yhi[(size_t)i * DIM + l * 4]) = hv;
        *reinterpret_cast<ushort4*>(&Ylo[(size_t)i * DIM + l * 4]) = lv;
    } else {
        reinterpret_cast<float4*>(Y)[(size_t)i * 32 + l] = acc;
    }
}

// ---------------- MFMA split-bf16 GEMM, B panel register-resident ----------------
// C[m,n] = sum_k A[m,k]*B[n,k]; a*b ~= ah*bh + ah*bl + al*bh (fp32 acc).
// Block = 4 waves, each wave: 32 rows x WN cols. B panel (WN x K, hi+lo) loaded
// into 128 VGPRs once per wave, amortized over CHUNK=2 m-tiles; k-loop then has
// only independent A loads (16 x b128 per 128-k half) feeding 96 MFMAs.
template <int K, int WN, bool RELU, bool BIAS, bool SPLIT_OUT>
__global__ __launch_bounds__(256, 2) void gemm_mfma_reg(
        const u16* __restrict__ Ahi, const u16* __restrict__ Alo,
        const u16* __restrict__ Bhi, const u16* __restrict__ Blo,
        const float* __restrict__ bias, float* __restrict__ C,
        u16* __restrict__ Chi, u16* __restrict__ Clo, int M, int N) {
    constexpr int WN16 = WN / 16;   // n-frags per wave
    constexpr int KS4  = K / 32;    // total k-steps
    constexpr int KH   = K / 128;   // 128-wide k-halves
    const int wave = threadIdx.x >> 6;
    const int lane = threadIdx.x & 63;
    const int lr = lane & 15;   // fragment row/col
    const int lq = lane >> 4;   // k-quad (8 elems)
    const int n0 = blockIdx.x * WN;

    // --- B panel into registers (L2-resident weights) ---
    bf16x8 Bh[WN16][KS4], Bl[WN16][KS4];
    #pragma unroll
    for (int nf = 0; nf < WN16; ++nf) {
        const u16* bh = Bhi + (size_t)(n0 + nf * 16 + lr) * K + lq * 8;
        const u16* bl = Blo + (size_t)(n0 + nf * 16 + lr) * K + lq * 8;
        #pragma unroll
        for (int ks = 0; ks < KS4; ++ks) {
            Bh[nf][ks] = ldfrag(bh + ks * 32);
            Bl[nf][ks] = ldfrag(bl + ks * 32);
        }
    }

    #pragma unroll 1
    for (int mt = 0; mt < 2; ++mt) {
        const int bt = blockIdx.y * 2 + mt;
        if (bt * 128 >= M) continue;
        const int mbase = bt * 128 + wave * 32;
        const int ar0 = min(mbase + lr,      M - 1);
        const int ar1 = min(mbase + 16 + lr, M - 1);
        const u16* pa0h = Ahi + (size_t)ar0 * K + lq * 8;
        const u16* pa0l = Alo + (size_t)ar0 * K + lq * 8;
        const u16* pa1h = Ahi + (size_t)ar1 * K + lq * 8;
        const u16* pa1l = Alo + (size_t)ar1 * K + lq * 8;

        f32x4 acc[2][WN16] = {};
        #pragma unroll
        for (int kh = 0; kh < KH; ++kh) {
            bf16x8 a0h[4], a0l[4], a1h[4], a1l[4];
            #pragma unroll
            for (int ks = 0; ks < 4; ++ks) {
                int ko = kh * 128 + ks * 32;
                a0h[ks] = ldfrag(pa0h + ko);
                a0l[ks] = ldfrag(pa0l + ko);
                a1h[ks] = ldfrag(pa1h + ko);
                a1l[ks] = ldfrag(pa1l + ko);
            }
            #pragma unroll
            for (int ks = 0; ks < 4; ++ks) {
                #pragma unroll
                for (int nf = 0; nf < WN16; ++nf) {
                    acc[0][nf] = MFMA16(a0h[ks], Bh[nf][kh * 4 + ks], acc[0][nf]);
                    acc[0][nf] = MFMA16(a0h[ks], Bl[nf][kh * 4 + ks], acc[0][nf]);
                    acc[0][nf] = MFMA16(a0l[ks], Bh[nf][kh * 4 + ks], acc[0][nf]);
                    acc[1][nf] = MFMA16(a1h[ks], Bh[nf][kh * 4 + ks], acc[1][nf]);
                    acc[1][nf] = MFMA16(a1h[ks], Bl[nf][kh * 4 + ks], acc[1][nf]);
                    acc[1][nf] = MFMA16(a1l[ks], Bh[nf][kh * 4 + ks], acc[1][nf]);
                }
            }
        }

        // epilogue: C/D layout col = lane&15 (n), row = (lane>>4)*4 + i (m)
        #pragma unroll
        for (int mf = 0; mf < 2; ++mf) {
            #pragma unroll
            for (int i = 0; i < 4; ++i) {
                int m = mbase + mf * 16 + lq * 4 + i;
                if (m >= M) continue;
                #pragma unroll
                for (int nf = 0; nf < WN16; ++nf) {
                    int n = n0 + nf * 16 + lr;
                    float v = acc[mf][nf][i];
                    if (BIAS) v += bias[n];
                    if (RELU) v = fmaxf(v, 0.f);
                    if (SPLIT_OUT) {
                        u16 h, l; split2(v, h, l);
                        Chi[(size_t)m * N + n] = h;
                        Clo[(size_t)m * N + n] = l;
                    } else {
                        C[(size_t)m * N + n] = v;
                    }
                }
            }
        }
    }
}

extern "C" void kernel_launch(void* const* d_in, const int* in_sizes, int n_in,
                              void* d_out, int out_size, void* d_ws, size_t ws_size,
                              hipStream_t stream) {
    const float* x  = (const float*)d_in[0];
    const int*   ei = (const int*)d_in[1];
    const float* W1 = (const float*)d_in[2];
    const float* b1 = (const float*)d_in[3];
    const float* W2 = (const float*)d_in[4];
    const float* b2 = (const float*)d_in[5];
    float* out = (float*)d_out;

    const int N = NNODES;
    const int E = in_sizes[1] / 2;
    const int IN_D = 128, HID = 256;
    const int* row = ei;
    const int* col = ei + E;

    // workspace carve-out (aligned to 256B)
    char* ws = (char*)d_ws;
    size_t off = 0;
    auto carve = [&](size_t bytes) { void* p = ws + off; off += (bytes + 255) & ~size_t(255); return p; };
    int*   cnt     = (int*)carve((size_t)N * 4);
    int*   row_ptr = (int*)carve((size_t)(N + 1) * 4);
    int*   cursor  = (int*)carve((size_t)N * 4);
    float* dinv    = (float*)carve((size_t)N * 4);
    int*   bsum    = (int*)carve((size_t)64 * 4);
    int*   cols    = (int*)carve((size_t)E * 4);
    u16*   w1hi    = (u16*)carve((size_t)HID * IN_D * 2);
    u16*   w1lo    = (u16*)carve((size_t)HID * IN_D * 2);
    u16*   w2hi    = (u16*)carve((size_t)IN_D * HID * 2);
    u16*   w2lo    = (u16*)carve((size_t)IN_D * HID * 2);
    u16*   y1hi    = (u16*)carve((size_t)N * IN_D * 2);   // 12.8 MB
    u16*   y1lo    = (u16*)carve((size_t)N * IN_D * 2);   // 12.8 MB
    u16*   hhi     = (u16*)carve((size_t)N * HID * 2);    // 25.6 MB
    u16*   hlo     = (u16*)carve((size_t)N * HID * 2);    // 25.6 MB
    float* z       = (float*)y1hi;   // y1 split dead after GEMM1; reuse for z

    const int TB = 256;
    const int nscan = (N + SCAN_CHUNK - 1) / SCAN_CHUNK;   // 25
    // 1) CSR build + weight splits
    cnt_init<<<(N + TB - 1) / TB, TB, 0, stream>>>(cnt, N);
    deg_count<<<(E + TB - 1) / TB, TB, 0, stream>>>(row, cnt, E);
    block_sums<<<nscan, TB, 0, stream>>>(cnt, bsum, N);
    scan_write<<<nscan, TB, 0, stream>>>(cnt, bsum, nscan, row_ptr, cursor, dinv, N);
    scatter_edges<<<(E + TB - 1) / TB, TB, 0, stream>>>(row, col, cursor, cols, E);
    split_f32<<<(HID * IN_D + TB - 1) / TB, TB, 0, stream>>>(W1, w1hi, w1lo, HID * IN_D);
    split_f32<<<(IN_D * HID + TB - 1) / TB, TB, 0, stream>>>(W2, w2hi, w2lo, IN_D * HID);

    // 2) y1 = A' x   (split bf16 out)
    spmm_csr<true, false><<<(N * 32 + TB - 1) / TB, TB, 0, stream>>>(
        row_ptr, cols, dinv, x, nullptr, nullptr, y1hi, y1lo, N);

    const int mtiles = (N + 127) / 128;          // 391
    const int gy = (mtiles + 1) / 2;             // CHUNK=2 -> 196
    // 3) h = relu(y1 @ W1^T + b1)   [N,128] -> [N,256], split out
    {
        dim3 grid(HID / 64, gy);
        gemm_mfma_reg<128, 64, true, true, true><<<grid, 256, 0, stream>>>(
            y1hi, y1lo, w1hi, w1lo, b1, nullptr, hhi, hlo, N, HID);
    }

    // 4) z = h @ W2^T               [N,256] -> [N,128] fp32 (b2 deferred)
    {
        dim3 grid(IN_D / 32, gy);
        gemm_mfma_reg<256, 32, false, false, false><<<grid, 256, 0, stream>>>(
            hhi, hlo, w2hi, w2lo, nullptr, z, nullptr, nullptr, N, IN_D);
    }

    // 5) out = A' z + b2
    spmm_csr<false, true><<<(N * 32 + TB - 1) / TB, TB, 0, stream>>>(
        row_ptr, cols, dinv, z, b2, out, nullptr, nullptr, N);
}

// Round 6
// 266.486 us; speedup vs baseline: 10.7553x; 1.1989x over previous
//
#include <hip/hip_runtime.h>
#include <hip/hip_bf16.h>

#define NNODES 50000
#define DIM 128   // both SPMMs run on 128 dims after the W2 reorder
#define SCAN_CHUNK 2048   // 256 threads * 8 elements

typedef unsigned short u16;
typedef _Float16 f16;
typedef short  bf16x8 __attribute__((ext_vector_type(8)));
typedef float  f32x4  __attribute__((ext_vector_type(4)));
typedef _Float16 f16x4 __attribute__((ext_vector_type(4)));

#define MFMA16(a, b, c) __builtin_amdgcn_mfma_f32_16x16x32_bf16((a), (b), (c), 0, 0, 0)

// ---------------- bf16 split helpers ----------------
__device__ __forceinline__ u16 bf16_rne(float f) {
    unsigned u = __builtin_bit_cast(unsigned, f);
    u += 0x7fffu + ((u >> 16) & 1u);
    return (u16)(u >> 16);
}
__device__ __forceinline__ void split2(float f, u16& hi, u16& lo) {
    u16 h = bf16_rne(f);
    float hf = __builtin_bit_cast(float, (unsigned)h << 16);
    hi = h;
    lo = bf16_rne(f - hf);
}
__device__ __forceinline__ bf16x8 ldfrag(const u16* p) {
    return *reinterpret_cast<const bf16x8*>(p);
}

// ---------------- degree count ----------------
__global__ void cnt_init(int* __restrict__ cnt, int n) {
    int i = blockIdx.x * blockDim.x + threadIdx.x;
    if (i < n) cnt[i] = 0;
}

__global__ void deg_count(const int* __restrict__ row, int* __restrict__ cnt, int nE) {
    int e = blockIdx.x * blockDim.x + threadIdx.x;
    if (e < nE) atomicAdd(&cnt[row[e]], 1);
}

// ---------------- weight split fp32 -> (hi, lo) bf16 ----------------
__global__ void split_f32(const float* __restrict__ w, u16* __restrict__ hi,
                          u16* __restrict__ lo, int n) {
    int i = blockIdx.x * blockDim.x + threadIdx.x;
    if (i < n) { u16 h, l; split2(w[i], h, l); hi[i] = h; lo[i] = l; }
}

// ---------------- fp32 -> fp16 convert (vectorized x4) ----------------
__global__ void f32_to_f16(const float* __restrict__ in, f16* __restrict__ out, int n4) {
    int i = blockIdx.x * blockDim.x + threadIdx.x;
    if (i < n4) {
        float4 v = reinterpret_cast<const float4*>(in)[i];
        f16x4 o = { (f16)v.x, (f16)v.y, (f16)v.z, (f16)v.w };
        reinterpret_cast<f16x4*>(out)[i] = o;
    }
}

// ---------------- multi-block exclusive scan ----------------
__global__ __launch_bounds__(256) void block_sums(const int* __restrict__ cnt,
                                                  int* __restrict__ bsum, int n) {
    __shared__ int red[256];
    int b = blockIdx.x, t = threadIdx.x;
    int base = b * SCAN_CHUNK + t * 8;
    int s = 0;
    #pragma unroll
    for (int k = 0; k < 8; ++k) { int i = base + k; if (i < n) s += cnt[i]; }
    red[t] = s;
    __syncthreads();
    for (int off = 128; off > 0; off >>= 1) {
        if (t < off) red[t] += red[t + off];
        __syncthreads();
    }
    if (t == 0) bsum[b] = red[0];
}

__global__ __launch_bounds__(256) void scan_write(const int* __restrict__ cnt,
                                                  const int* __restrict__ bsum, int nblocks,
                                                  int* __restrict__ row_ptr, int* __restrict__ cursor,
                                                  float* __restrict__ dinv, int n) {
    __shared__ int ssum[256];
    int b = blockIdx.x, t = threadIdx.x;
    int boff = 0, total = 0;
    for (int k = 0; k < nblocks; ++k) { int v = bsum[k]; boff += (k < b) ? v : 0; total += v; }
    int base = b * SCAN_CHUNK + t * 8;
    int local[8]; int s = 0;
    #pragma unroll
    for (int k = 0; k < 8; ++k) { int i = base + k; local[k] = (i < n) ? cnt[i] : 0; s += local[k]; }
    ssum[t] = s;
    __syncthreads();
    for (int off = 1; off < 256; off <<= 1) {
        int v = (t >= off) ? ssum[t - off] : 0;
        __syncthreads();
        ssum[t] += v;
        __syncthreads();
    }
    int run = boff + ((t == 0) ? 0 : ssum[t - 1]);
    #pragma unroll
    for (int k = 0; k < 8; ++k) {
        int i = base + k;
        if (i < n) {
            row_ptr[i] = run;
            cursor[i]  = run;
            dinv[i] = rsqrtf((float)(local[k] + 1));
            run += local[k];
        }
    }
    if (b == 0 && t == 0) row_ptr[n] = total;
}

// ---------------- scatter edges into CSR (+ per-edge value) ----------------
__global__ void scatter_edges(const int* __restrict__ row, const int* __restrict__ col,
                              const float* __restrict__ dinv, int* __restrict__ cursor,
                              int* __restrict__ cols, float* __restrict__ vals, int nE) {
    int e = blockIdx.x * blockDim.x + threadIdx.x;
    if (e < nE) {
        int r = row[e], c = col[e];
        int pos = atomicAdd(&cursor[r], 1);
        cols[pos] = c;
        vals[pos] = dinv[r] * dinv[c];
    }
}

// ---------------- CSR SPMM: fp16 gather, batched-8 MLP, no fp atomics ----------------
// Y[i,:] = dinv[i]^2 * X[i,:] + sum_j vals_j * X[c_j,:]  (+ bias)
template <bool SPLIT_OUT, bool BIAS>
__global__ __launch_bounds__(256) void spmm_csr_h(const int* __restrict__ row_ptr,
                         const int* __restrict__ cols, const float* __restrict__ vals,
                         const f16* __restrict__ Xh, const float* __restrict__ dinv,
                         const float* __restrict__ bias,
                         float* __restrict__ Y, u16* __restrict__ Yhi, u16* __restrict__ Ylo,
                         int n) {
    int tid = blockIdx.x * blockDim.x + threadIdx.x;
    int i = tid >> 5;        // node
    int l = tid & 31;        // 4-elem slot (DIM/4 == 32)
    if (i >= n) return;
    const f16x4* X4 = reinterpret_cast<const f16x4*>(Xh);
    float di = dinv[i];
    float s2 = di * di;
    f16x4 xv = X4[(size_t)i * 32 + l];
    float4 acc;
    acc.x = s2 * (float)xv[0]; acc.y = s2 * (float)xv[1];
    acc.z = s2 * (float)xv[2]; acc.w = s2 * (float)xv[3];
    int s = row_ptr[i], e = row_ptr[i + 1];
    for (int j = s; j < e; j += 8) {
        int c[8]; float w[8];
        #pragma unroll
        for (int t = 0; t < 8; ++t) {
            int idx = j + t;
            bool ok = idx < e;
            idx = ok ? idx : (e - 1);      // clamp: dup gathers hit L1, w=0 kills them
            c[t] = cols[idx];
            w[t] = ok ? vals[idx] : 0.f;
        }
        f16x4 g[8];
        #pragma unroll
        for (int t = 0; t < 8; ++t) g[t] = X4[(size_t)c[t] * 32 + l];
        #pragma unroll
        for (int t = 0; t < 8; ++t) {
            acc.x += w[t] * (float)g[t][0];
            acc.y += w[t] * (float)g[t][1];
            acc.z += w[t] * (float)g[t][2];
            acc.w += w[t] * (float)g[t][3];
        }
    }
    if (BIAS) {
        float4 b = reinterpret_cast<const float4*>(bias)[l];
        acc.x += b.x; acc.y += b.y; acc.z += b.z; acc.w += b.w;
    }
    if (SPLIT_OUT) {
        ushort4 hv, lv;
        split2(acc.x, hv.x, lv.x); split2(acc.y, hv.y, lv.y);
        split2(acc.z, hv.z, lv.z); split2(acc.w, hv.w, lv.w);
        *reinterpret_cast<ushort4*>(&Yhi[(size_t)i * DIM + l * 4]) = hv;
        *reinterpret_cast<ushort4*>(&Ylo[(size_t)i * DIM + l * 4]) = lv;
    } else {
        reinterpret_cast<float4*>(Y)[(size_t)i * 32 + l] = acc;
    }
}

// ---------------- MFMA split-bf16 GEMM, B panel register-resident ----------------
// OMODE: 0 = fp32 out, 1 = split bf16 (hi/lo), 2 = fp16 out
template <int K, int WN, bool RELU, bool BIAS, int OMODE>
__global__ __launch_bounds__(256, 2) void gemm_mfma_reg(
        const u16* __restrict__ Ahi, const u16* __restrict__ Alo,
        const u16* __restrict__ Bhi, const u16* __restrict__ Blo,
        const float* __restrict__ bias, float* __restrict__ C,
        u16* __restrict__ Chi, u16* __restrict__ Clo, f16* __restrict__ Ch,
        int M, int N) {
    constexpr int WN16 = WN / 16;   // n-frags per wave
    constexpr int KS4  = K / 32;    // total k-steps
    constexpr int KH   = K / 128;   // 128-wide k-halves
    const int wave = threadIdx.x >> 6;
    const int lane = threadIdx.x & 63;
    const int lr = lane & 15;   // fragment row/col
    const int lq = lane >> 4;   // k-quad (8 elems)
    const int n0 = blockIdx.x * WN;

    // --- B panel into registers (L2-resident weights) ---
    bf16x8 Bh[WN16][KS4], Bl[WN16][KS4];
    #pragma unroll
    for (int nf = 0; nf < WN16; ++nf) {
        const u16* bh = Bhi + (size_t)(n0 + nf * 16 + lr) * K + lq * 8;
        const u16* bl = Blo + (size_t)(n0 + nf * 16 + lr) * K + lq * 8;
        #pragma unroll
        for (int ks = 0; ks < KS4; ++ks) {
            Bh[nf][ks] = ldfrag(bh + ks * 32);
            Bl[nf][ks] = ldfrag(bl + ks * 32);
        }
    }

    #pragma unroll 1
    for (int mt = 0; mt < 2; ++mt) {
        const int bt = blockIdx.y * 2 + mt;
        if (bt * 128 >= M) continue;
        const int mbase = bt * 128 + wave * 32;
        const int ar0 = min(mbase + lr,      M - 1);
        const int ar1 = min(mbase + 16 + lr, M - 1);
        const u16* pa0h = Ahi + (size_t)ar0 * K + lq * 8;
        const u16* pa0l = Alo + (size_t)ar0 * K + lq * 8;
        const u16* pa1h = Ahi + (size_t)ar1 * K + lq * 8;
        const u16* pa1l = Alo + (size_t)ar1 * K + lq * 8;

        f32x4 acc[2][WN16] = {};
        #pragma unroll
        for (int kh = 0; kh < KH; ++kh) {
            bf16x8 a0h[4], a0l[4], a1h[4], a1l[4];
            #pragma unroll
            for (int ks = 0; ks < 4; ++ks) {
                int ko = kh * 128 + ks * 32;
                a0h[ks] = ldfrag(pa0h + ko);
                a0l[ks] = ldfrag(pa0l + ko);
                a1h[ks] = ldfrag(pa1h + ko);
                a1l[ks] = ldfrag(pa1l + ko);
            }
            #pragma unroll
            for (int ks = 0; ks < 4; ++ks) {
                #pragma unroll
                for (int nf = 0; nf < WN16; ++nf) {
                    acc[0][nf] = MFMA16(a0h[ks], Bh[nf][kh * 4 + ks], acc[0][nf]);
                    acc[0][nf] = MFMA16(a0h[ks], Bl[nf][kh * 4 + ks], acc[0][nf]);
                    acc[0][nf] = MFMA16(a0l[ks], Bh[nf][kh * 4 + ks], acc[0][nf]);
                    acc[1][nf] = MFMA16(a1h[ks], Bh[nf][kh * 4 + ks], acc[1][nf]);
                    acc[1][nf] = MFMA16(a1h[ks], Bl[nf][kh * 4 + ks], acc[1][nf]);
                    acc[1][nf] = MFMA16(a1l[ks], Bh[nf][kh * 4 + ks], acc[1][nf]);
                }
            }
        }

        // epilogue: C/D layout col = lane&15 (n), row = (lane>>4)*4 + i (m)
        #pragma unroll
        for (int mf = 0; mf < 2; ++mf) {
            #pragma unroll
            for (int i = 0; i < 4; ++i) {
                int m = mbase + mf * 16 + lq * 4 + i;
                if (m >= M) continue;
                #pragma unroll
                for (int nf = 0; nf < WN16; ++nf) {
                    int n = n0 + nf * 16 + lr;
                    float v = acc[mf][nf][i];
                    if (BIAS) v += bias[n];
                    if (RELU) v = fmaxf(v, 0.f);
                    if (OMODE == 1) {
                        u16 h, l; split2(v, h, l);
                        Chi[(size_t)m * N + n] = h;
                        Clo[(size_t)m * N + n] = l;
                    } else if (OMODE == 2) {
                        Ch[(size_t)m * N + n] = (f16)v;
                    } else {
                        C[(size_t)m * N + n] = v;
                    }
                }
            }
        }
    }
}

extern "C" void kernel_launch(void* const* d_in, const int* in_sizes, int n_in,
                              void* d_out, int out_size, void* d_ws, size_t ws_size,
                              hipStream_t stream) {
    const float* x  = (const float*)d_in[0];
    const int*   ei = (const int*)d_in[1];
    const float* W1 = (const float*)d_in[2];
    const float* b1 = (const float*)d_in[3];
    const float* W2 = (const float*)d_in[4];
    const float* b2 = (const float*)d_in[5];
    float* out = (float*)d_out;

    const int N = NNODES;
    const int E = in_sizes[1] / 2;
    const int IN_D = 128, HID = 256;
    const int* row = ei;
    const int* col = ei + E;

    // workspace carve-out (aligned to 256B)
    char* ws = (char*)d_ws;
    size_t off = 0;
    auto carve = [&](size_t bytes) { void* p = ws + off; off += (bytes + 255) & ~size_t(255); return p; };
    int*   cnt     = (int*)carve((size_t)N * 4);
    int*   row_ptr = (int*)carve((size_t)(N + 1) * 4);
    int*   cursor  = (int*)carve((size_t)N * 4);
    float* dinv    = (float*)carve((size_t)N * 4);
    int*   bsum    = (int*)carve((size_t)64 * 4);
    int*   cols    = (int*)carve((size_t)E * 4);
    float* vals    = (float*)carve((size_t)E * 4);
    u16*   w1hi    = (u16*)carve((size_t)HID * IN_D * 2);
    u16*   w1lo    = (u16*)carve((size_t)HID * IN_D * 2);
    u16*   w2hi    = (u16*)carve((size_t)IN_D * HID * 2);
    u16*   w2lo    = (u16*)carve((size_t)IN_D * HID * 2);
    f16*   xh      = (f16*)carve((size_t)N * IN_D * 2);   // 12.8 MB
    u16*   y1hi    = (u16*)carve((size_t)N * IN_D * 2);   // 12.8 MB
    u16*   y1lo    = (u16*)carve((size_t)N * IN_D * 2);   // 12.8 MB
    u16*   hhi     = (u16*)carve((size_t)N * HID * 2);    // 25.6 MB
    u16*   hlo     = (u16*)carve((size_t)N * HID * 2);    // 25.6 MB
    f16*   zh      = (f16*)y1hi;   // y1 split dead after GEMM1; reuse for z (fp16)

    const int TB = 256;
    const int nscan = (N + SCAN_CHUNK - 1) / SCAN_CHUNK;   // 25
    // 1) CSR build (+ per-edge vals) + weight splits + x fp16 copy
    cnt_init<<<(N + TB - 1) / TB, TB, 0, stream>>>(cnt, N);
    deg_count<<<(E + TB - 1) / TB, TB, 0, stream>>>(row, cnt, E);
    block_sums<<<nscan, TB, 0, stream>>>(cnt, bsum, N);
    scan_write<<<nscan, TB, 0, stream>>>(cnt, bsum, nscan, row_ptr, cursor, dinv, N);
    scatter_edges<<<(E + TB - 1) / TB, TB, 0, stream>>>(row, col, dinv, cursor, cols, vals, E);
    split_f32<<<(HID * IN_D + TB - 1) / TB, TB, 0, stream>>>(W1, w1hi, w1lo, HID * IN_D);
    split_f32<<<(IN_D * HID + TB - 1) / TB, TB, 0, stream>>>(W2, w2hi, w2lo, IN_D * HID);
    f32_to_f16<<<((N * IN_D / 4) + TB - 1) / TB, TB, 0, stream>>>(x, xh, N * IN_D / 4);

    // 2) y1 = A' x   (fp16 gather -> split bf16 out)
    spmm_csr_h<true, false><<<(N * 32 + TB - 1) / TB, TB, 0, stream>>>(
        row_ptr, cols, vals, xh, dinv, nullptr, nullptr, y1hi, y1lo, N);

    const int mtiles = (N + 127) / 128;          // 391
    const int gy = (mtiles + 1) / 2;             // CHUNK=2 -> 196
    // 3) h = relu(y1 @ W1^T + b1)   [N,128] -> [N,256], split out
    {
        dim3 grid(HID / 64, gy);
        gemm_mfma_reg<128, 64, true, true, 1><<<grid, 256, 0, stream>>>(
            y1hi, y1lo, w1hi, w1lo, b1, nullptr, hhi, hlo, nullptr, N, HID);
    }

    // 4) z = h @ W2^T   [N,256] -> [N,128] fp16 out (b2 deferred past SPMM2)
    {
        dim3 grid(IN_D / 32, gy);
        gemm_mfma_reg<256, 32, false, false, 2><<<grid, 256, 0, stream>>>(
            hhi, hlo, w2hi, w2lo, nullptr, nullptr, nullptr, nullptr, zh, N, IN_D);
    }

    // 5) out = A' z + b2   (fp16 gather -> fp32 out)
    spmm_csr_h<false, true><<<(N * 32 + TB - 1) / TB, TB, 0, stream>>>(
        row_ptr, cols, vals, zh, dinv, b2, out, nullptr, nullptr, N);
}

// Round 7
// 221.122 us; speedup vs baseline: 12.9618x; 1.2052x over previous
//
#include <hip/hip_runtime.h>
#include <hip/hip_bf16.h>

#define NNODES 50000
#define DIM 128   // both SPMMs run on 128 dims after the W2 reorder
#define SCAN_CHUNK 2048   // 256 threads * 8 elements

typedef unsigned short u16;
typedef _Float16 f16;
typedef float  f32x4  __attribute__((ext_vector_type(4)));
typedef _Float16 f16x4v __attribute__((ext_vector_type(4)));
typedef _Float16 f16x8 __attribute__((ext_vector_type(8)));

#define MFMAH(a, b, c) __builtin_amdgcn_mfma_f32_16x16x32_f16((a), (b), (c), 0, 0, 0)

// ---------------- degree count ----------------
__global__ void cnt_init(int* __restrict__ cnt, int n) {
    int i = blockIdx.x * blockDim.x + threadIdx.x;
    if (i < n) cnt[i] = 0;
}

__global__ void deg_count(const int* __restrict__ row, int* __restrict__ cnt, int nE) {
    int e = blockIdx.x * blockDim.x + threadIdx.x;
    if (e < nE) atomicAdd(&cnt[row[e]], 1);
}

// ---------------- fp32 -> fp16 convert (vectorized x4) ----------------
__global__ void f32_to_f16(const float* __restrict__ in, f16* __restrict__ out, int n4) {
    int i = blockIdx.x * blockDim.x + threadIdx.x;
    if (i < n4) {
        float4 v = reinterpret_cast<const float4*>(in)[i];
        f16x4v o = { (f16)v.x, (f16)v.y, (f16)v.z, (f16)v.w };
        reinterpret_cast<f16x4v*>(out)[i] = o;
    }
}

// ---------------- multi-block exclusive scan ----------------
__global__ __launch_bounds__(256) void block_sums(const int* __restrict__ cnt,
                                                  int* __restrict__ bsum, int n) {
    __shared__ int red[256];
    int b = blockIdx.x, t = threadIdx.x;
    int base = b * SCAN_CHUNK + t * 8;
    int s = 0;
    #pragma unroll
    for (int k = 0; k < 8; ++k) { int i = base + k; if (i < n) s += cnt[i]; }
    red[t] = s;
    __syncthreads();
    for (int off = 128; off > 0; off >>= 1) {
        if (t < off) red[t] += red[t + off];
        __syncthreads();
    }
    if (t == 0) bsum[b] = red[0];
}

__global__ __launch_bounds__(256) void scan_write(const int* __restrict__ cnt,
                                                  const int* __restrict__ bsum, int nblocks,
                                                  int* __restrict__ row_ptr, int* __restrict__ cursor,
                                                  float* __restrict__ dinv, int n) {
    __shared__ int ssum[256];
    int b = blockIdx.x, t = threadIdx.x;
    int boff = 0, total = 0;
    for (int k = 0; k < nblocks; ++k) { int v = bsum[k]; boff += (k < b) ? v : 0; total += v; }
    int base = b * SCAN_CHUNK + t * 8;
    int local[8]; int s = 0;
    #pragma unroll
    for (int k = 0; k < 8; ++k) { int i = base + k; local[k] = (i < n) ? cnt[i] : 0; s += local[k]; }
    ssum[t] = s;
    __syncthreads();
    for (int off = 1; off < 256; off <<= 1) {
        int v = (t >= off) ? ssum[t - off] : 0;
        __syncthreads();
        ssum[t] += v;
        __syncthreads();
    }
    int run = boff + ((t == 0) ? 0 : ssum[t - 1]);
    #pragma unroll
    for (int k = 0; k < 8; ++k) {
        int i = base + k;
        if (i < n) {
            row_ptr[i] = run;
            cursor[i]  = run;
            dinv[i] = rsqrtf((float)(local[k] + 1));
            run += local[k];
        }
    }
    if (b == 0 && t == 0) row_ptr[n] = total;
}

// ---------------- scatter edges into CSR: ONE packed 8B store per edge ----------------
__global__ void scatter_edges(const int* __restrict__ row, const int* __restrict__ col,
                              const float* __restrict__ dinv, int* __restrict__ cursor,
                              uint2* __restrict__ cv, int nE) {
    int e = blockIdx.x * blockDim.x + threadIdx.x;
    if (e < nE) {
        int r = row[e], c = col[e];
        int pos = atomicAdd(&cursor[r], 1);
        float v = dinv[r] * dinv[c];
        cv[pos] = make_uint2((unsigned)c, __builtin_bit_cast(unsigned, v));
    }
}

// ---------------- CSR SPMM: fp16 gather, batched-8 MLP, packed (col,val) ----------------
// Y[i,:] = dinv[i]^2 * X[i,:] + sum_j val_j * X[c_j,:]  (+ bias)
template <bool OUT16, bool BIAS>
__global__ __launch_bounds__(256) void spmm_csr_h(const int* __restrict__ row_ptr,
                         const uint2* __restrict__ cv,
                         const f16* __restrict__ Xh, const float* __restrict__ dinv,
                         const float* __restrict__ bias,
                         float* __restrict__ Y, f16* __restrict__ Yh, int n) {
    int tid = blockIdx.x * blockDim.x + threadIdx.x;
    int i = tid >> 5;        // node
    int l = tid & 31;        // 4-elem slot (DIM/4 == 32)
    if (i >= n) return;
    const f16x4v* X4 = reinterpret_cast<const f16x4v*>(Xh);
    float di = dinv[i];
    float s2 = di * di;
    f16x4v xv = X4[(size_t)i * 32 + l];
    float4 acc;
    acc.x = s2 * (float)xv[0]; acc.y = s2 * (float)xv[1];
    acc.z = s2 * (float)xv[2]; acc.w = s2 * (float)xv[3];
    int s = row_ptr[i], e = row_ptr[i + 1];
    for (int j = s; j < e; j += 8) {
        int c[8]; float w[8];
        #pragma unroll
        for (int t = 0; t < 8; ++t) {
            int idx = j + t;
            bool ok = idx < e;
            idx = ok ? idx : (e - 1);      // clamp: dup gathers hit L1, w=0 kills them
            uint2 p = cv[idx];
            c[t] = (int)p.x;
            w[t] = ok ? __builtin_bit_cast(float, p.y) : 0.f;
        }
        f16x4v g[8];
        #pragma unroll
        for (int t = 0; t < 8; ++t) g[t] = X4[(size_t)c[t] * 32 + l];
        #pragma unroll
        for (int t = 0; t < 8; ++t) {
            acc.x += w[t] * (float)g[t][0];
            acc.y += w[t] * (float)g[t][1];
            acc.z += w[t] * (float)g[t][2];
            acc.w += w[t] * (float)g[t][3];
        }
    }
    if (BIAS) {
        float4 b = reinterpret_cast<const float4*>(bias)[l];
        acc.x += b.x; acc.y += b.y; acc.z += b.z; acc.w += b.w;
    }
    if (OUT16) {
        f16x4v o = { (f16)acc.x, (f16)acc.y, (f16)acc.z, (f16)acc.w };
        *reinterpret_cast<f16x4v*>(&Yh[(size_t)i * DIM + l * 4]) = o;
    } else {
        reinterpret_cast<float4*>(Y)[(size_t)i * 32 + l] = acc;
    }
}

// ---------------- fused MLP: z = (relu(y1 @ W1^T + b1)) @ W2^T, all f16 MFMA ----------------
// Barrier-free: each wave owns 32 rows end-to-end; h lives in wave-private LDS.
// Phase 1 SWAPPED (A=W1, B=y1): D[hcol][node] -> lane lr = node-row, so each lane
// holds 4 consecutive h-cols per frag -> packed 8B LDS writes, row-major h.
// Phase 2 SWAPPED (A=W2, B=h): D[zcol][node] -> packed 8B global z writes.
// z is written IN-PLACE over y1 (same rows, all reads precede writes per-wave).
__global__ __launch_bounds__(256, 2) void mlp_fused(
        const f16* __restrict__ y1, const f16* __restrict__ w1,
        const float* __restrict__ b1, const f16* __restrict__ w2,
        f16* __restrict__ z, int M) {
    constexpr int HSTR = 264;                 // 256 + 8 pad: 16B-aligned rows
    __shared__ f16 hl[4][32][HSTR];           // 66 KB -> 2 blocks/CU
    const int wave = threadIdx.x >> 6;
    const int lane = threadIdx.x & 63;
    const int lr = lane & 15;                 // fragment row/col index
    const int lq = lane >> 4;                 // k-quad (8 elems)
    const int mbase = blockIdx.x * 128 + wave * 32;

    // y1 B-frags for this wave's 32 rows, all k=128: read once, reuse all quarters.
    f16x8 yb[2][4];
    #pragma unroll
    for (int nf = 0; nf < 2; ++nf) {
        int r = min(mbase + nf * 16 + lr, M - 1);
        const f16* pr = y1 + (size_t)r * 128 + lq * 8;
        #pragma unroll
        for (int ks = 0; ks < 4; ++ks)
            yb[nf][ks] = *reinterpret_cast<const f16x8*>(pr + ks * 32);
    }

    // ---- phase 1: h = relu(y1 W1^T + b1), 4 quarters of 64 h-cols ----
    #pragma unroll 1
    for (int q = 0; q < 4; ++q) {
        const int hc0 = q * 64;
        f16x8 wa[4][4];
        #pragma unroll
        for (int mf = 0; mf < 4; ++mf) {
            const f16* pw = w1 + (size_t)(hc0 + mf * 16 + lr) * 128 + lq * 8;
            #pragma unroll
            for (int ks = 0; ks < 4; ++ks)
                wa[mf][ks] = *reinterpret_cast<const f16x8*>(pw + ks * 32);
        }
        f32x4 acc[4][2] = {};
        #pragma unroll
        for (int ks = 0; ks < 4; ++ks)
            #pragma unroll
            for (int mf = 0; mf < 4; ++mf)
                #pragma unroll
                for (int nf = 0; nf < 2; ++nf)
                    acc[mf][nf] = MFMAH(wa[mf][ks], yb[nf][ks], acc[mf][nf]);
        #pragma unroll
        for (int mf = 0; mf < 4; ++mf) {
            float4 bb = *reinterpret_cast<const float4*>(&b1[hc0 + mf * 16 + lq * 4]);
            #pragma unroll
            for (int nf = 0; nf < 2; ++nf) {
                f16x4v hv = { (f16)fmaxf(acc[mf][nf][0] + bb.x, 0.f),
                              (f16)fmaxf(acc[mf][nf][1] + bb.y, 0.f),
                              (f16)fmaxf(acc[mf][nf][2] + bb.z, 0.f),
                              (f16)fmaxf(acc[mf][nf][3] + bb.w, 0.f) };
                *reinterpret_cast<f16x4v*>(&hl[wave][nf * 16 + lr][hc0 + mf * 16 + lq * 4]) = hv;
            }
        }
    }

    // ---- phase 2: z = h W2^T  (wave-private LDS reads; no barrier needed) ----
    f32x4 acc2[8][2] = {};
    #pragma unroll 1
    for (int ks = 0; ks < 8; ++ks) {
        f16x8 hb[2];
        #pragma unroll
        for (int nf = 0; nf < 2; ++nf)
            hb[nf] = *reinterpret_cast<const f16x8*>(&hl[wave][nf * 16 + lr][ks * 32 + lq * 8]);
        f16x8 wa2[8];
        #pragma unroll
        for (int mf = 0; mf < 8; ++mf)
            wa2[mf] = *reinterpret_cast<const f16x8*>(w2 + (size_t)(mf * 16 + lr) * 256 + ks * 32 + lq * 8);
        #pragma unroll
        for (int mf = 0; mf < 8; ++mf)
            #pragma unroll
            for (int nf = 0; nf < 2; ++nf)
                acc2[mf][nf] = MFMAH(wa2[mf], hb[nf], acc2[mf][nf]);
    }
    #pragma unroll
    for (int nf = 0; nf < 2; ++nf) {
        int node = mbase + nf * 16 + lr;
        if (node >= M) continue;
        #pragma unroll
        for (int mf = 0; mf < 8; ++mf) {
            f16x4v zv = { (f16)acc2[mf][nf][0], (f16)acc2[mf][nf][1],
                          (f16)acc2[mf][nf][2], (f16)acc2[mf][nf][3] };
            *reinterpret_cast<f16x4v*>(z + (size_t)node * 128 + mf * 16 + lq * 4) = zv;
        }
    }
}

extern "C" void kernel_launch(void* const* d_in, const int* in_sizes, int n_in,
                              void* d_out, int out_size, void* d_ws, size_t ws_size,
                              hipStream_t stream) {
    const float* x  = (const float*)d_in[0];
    const int*   ei = (const int*)d_in[1];
    const float* W1 = (const float*)d_in[2];
    const float* b1 = (const float*)d_in[3];
    const float* W2 = (const float*)d_in[4];
    const float* b2 = (const float*)d_in[5];
    float* out = (float*)d_out;

    const int N = NNODES;
    const int E = in_sizes[1] / 2;
    const int IN_D = 128, HID = 256;
    const int* row = ei;
    const int* col = ei + E;

    // workspace carve-out (aligned to 256B)
    char* ws = (char*)d_ws;
    size_t off = 0;
    auto carve = [&](size_t bytes) { void* p = ws + off; off += (bytes + 255) & ~size_t(255); return p; };
    int*   cnt     = (int*)carve((size_t)N * 4);
    int*   row_ptr = (int*)carve((size_t)(N + 1) * 4);
    int*   cursor  = (int*)carve((size_t)N * 4);
    float* dinv    = (float*)carve((size_t)N * 4);
    int*   bsum    = (int*)carve((size_t)64 * 4);
    uint2* cv      = (uint2*)carve((size_t)E * 8);        // packed (col, val)
    f16*   w1h     = (f16*)carve((size_t)HID * IN_D * 2); // 64 KB
    f16*   w2h     = (f16*)carve((size_t)IN_D * HID * 2); // 64 KB
    f16*   xh      = (f16*)carve((size_t)N * IN_D * 2);   // 12.8 MB
    f16*   y1h     = (f16*)carve((size_t)N * IN_D * 2);   // 12.8 MB, becomes z in-place
    f16*   zh      = y1h;

    const int TB = 256;
    const int nscan = (N + SCAN_CHUNK - 1) / SCAN_CHUNK;   // 25
    // 1) CSR build (packed edges) + f16 conversions
    cnt_init<<<(N + TB - 1) / TB, TB, 0, stream>>>(cnt, N);
    deg_count<<<(E + TB - 1) / TB, TB, 0, stream>>>(row, cnt, E);
    block_sums<<<nscan, TB, 0, stream>>>(cnt, bsum, N);
    scan_write<<<nscan, TB, 0, stream>>>(cnt, bsum, nscan, row_ptr, cursor, dinv, N);
    scatter_edges<<<(E + TB - 1) / TB, TB, 0, stream>>>(row, col, dinv, cursor, cv, E);
    f32_to_f16<<<((HID * IN_D / 4) + TB - 1) / TB, TB, 0, stream>>>(W1, w1h, HID * IN_D / 4);
    f32_to_f16<<<((IN_D * HID / 4) + TB - 1) / TB, TB, 0, stream>>>(W2, w2h, IN_D * HID / 4);
    f32_to_f16<<<((N * IN_D / 4) + TB - 1) / TB, TB, 0, stream>>>(x, xh, N * IN_D / 4);

    // 2) y1 = A' x   (fp16 gather -> fp16 out)
    spmm_csr_h<true, false><<<(N * 32 + TB - 1) / TB, TB, 0, stream>>>(
        row_ptr, cv, xh, dinv, nullptr, nullptr, y1h, N);

    // 3+4) z = relu(y1 W1^T + b1) W2^T   (fused, z in-place over y1)
    mlp_fused<<<(N + 127) / 128, 256, 0, stream>>>(y1h, w1h, b1, w2h, zh, N);

    // 5) out = A' z + b2   (fp16 gather -> fp32 out)
    spmm_csr_h<false, true><<<(N * 32 + TB - 1) / TB, TB, 0, stream>>>(
        row_ptr, cv, zh, dinv, b2, out, nullptr, N);
}

// Round 8
// 159.207 us; speedup vs baseline: 18.0026x; 1.3889x over previous
//
#include <hip/hip_runtime.h>
#include <hip/hip_bf16.h>

#define NNODES 50000   // must stay < 65536 (row/col packed into one u32)
#define DIM 128        // both SPMMs run on 128 dims after the W2 reorder
#define NBUCK 196      // ceil(NNODES/256); bucket b covers rows [b*256, b*256+256)

typedef unsigned short u16;
typedef _Float16 f16;
typedef float  f32x4  __attribute__((ext_vector_type(4)));
typedef _Float16 f16x4v __attribute__((ext_vector_type(4)));
typedef _Float16 f16x8 __attribute__((ext_vector_type(8)));

#define MFMAH(a, b, c) __builtin_amdgcn_mfma_f32_16x16x32_f16((a), (b), (c), 0, 0, 0)

// ---------------- fp32 -> fp16 convert (vectorized x4) ----------------
__global__ void f32_to_f16(const float* __restrict__ in, f16* __restrict__ out, int n4) {
    int i = blockIdx.x * blockDim.x + threadIdx.x;
    if (i < n4) {
        float4 v = reinterpret_cast<const float4*>(in)[i];
        f16x4v o = { (f16)v.x, (f16)v.y, (f16)v.z, (f16)v.w };
        reinterpret_cast<f16x4v*>(out)[i] = o;
    }
}

// ---------------- pass A: per-bucket histogram (LDS -> global atomics) ----------------
__global__ __launch_bounds__(256) void bucket_hist(const int* __restrict__ row,
                                                   int* __restrict__ bcnt, int nE) {
    __shared__ int hist[256];
    int t = threadIdx.x;
    hist[t] = 0;
    __syncthreads();
    int base_e = blockIdx.x * 2048 + t;
    #pragma unroll
    for (int k = 0; k < 8; ++k) {
        int e = base_e + k * 256;
        if (e < nE) atomicAdd(&hist[(unsigned)row[e] >> 8], 1);
    }
    __syncthreads();
    if (hist[t] > 0) atomicAdd(&bcnt[t], hist[t]);
}

// ---------------- bucket exclusive scan -> bbase[NB+1], gcursor ----------------
__global__ __launch_bounds__(256) void bucket_scan(const int* __restrict__ bcnt,
                                                   int* __restrict__ bbase,
                                                   int* __restrict__ gcursor, int nb) {
    __shared__ int sc[256];
    int t = threadIdx.x;
    int v = (t < nb) ? bcnt[t] : 0;
    sc[t] = v;
    __syncthreads();
    for (int off = 1; off < 256; off <<= 1) {
        int u = (t >= off) ? sc[t - off] : 0;
        __syncthreads();
        sc[t] += u;
        __syncthreads();
    }
    if (t < nb) {
        int excl = sc[t] - v;
        bbase[t] = excl;
        gcursor[t] = excl;
    }
    if (t == 255) bbase[nb] = sc[255];   // total == E
}

// ---------------- pass B: place packed (row,col) edges grouped by bucket ----------------
// Per-(block,bucket) runs are contiguous -> ~80B store runs instead of random 4B.
__global__ __launch_bounds__(256) void bucket_place(const int* __restrict__ row,
                                                    const int* __restrict__ col,
                                                    int* __restrict__ gcursor,
                                                    unsigned* __restrict__ bkt, int nE) {
    __shared__ int hist[256];
    __shared__ int cur[256];
    int t = threadIdx.x;
    hist[t] = 0;
    __syncthreads();
    unsigned pk[8]; int valid = 0;
    int base_e = blockIdx.x * 2048 + t;
    #pragma unroll
    for (int k = 0; k < 8; ++k) {
        int e = base_e + k * 256;
        if (e < nE) {
            unsigned r = (unsigned)row[e], c = (unsigned)col[e];
            pk[k] = (r << 16) | c;
            valid |= 1 << k;
            atomicAdd(&hist[r >> 8], 1);
        }
    }
    __syncthreads();
    if (hist[t] > 0) cur[t] = atomicAdd(&gcursor[t], hist[t]);
    __syncthreads();
    #pragma unroll
    for (int k = 0; k < 8; ++k) {
        if (valid & (1 << k)) {
            int pos = atomicAdd(&cur[pk[k] >> 24], 1);   // pk>>24 == row>>8
            bkt[pos] = pk[k];
        }
    }
}

// ---------------- pass C: one block per bucket -> row_ptr, dinv, cols16 ----------------
// row_ptr[r] = bucket_base + intra-bucket prefix (no global deg pass needed).
// Fine scatter targets an L2-hot ~8-32KB segment -> writes back once.
__global__ __launch_bounds__(256) void csr_fill(const unsigned* __restrict__ bkt,
                                                const int* __restrict__ bbase,
                                                int* __restrict__ row_ptr,
                                                float* __restrict__ dinv,
                                                u16* __restrict__ cols16, int n) {
    __shared__ int lcnt[256], lscan[256], lcur[256];
    int b = blockIdx.x, t = threadIdx.x;
    int r0 = b << 8;
    int s = bbase[b], e = bbase[b + 1];
    lcnt[t] = 0;
    __syncthreads();
    for (int i = s + t; i < e; i += 256)
        atomicAdd(&lcnt[(bkt[i] >> 16) & 255], 1);
    __syncthreads();
    int v = lcnt[t];
    lscan[t] = v;
    __syncthreads();
    for (int off = 1; off < 256; off <<= 1) {
        int u = (t >= off) ? lscan[t - off] : 0;
        __syncthreads();
        lscan[t] += u;
        __syncthreads();
    }
    int gpos = s + lscan[t] - v;          // exclusive
    int r = r0 + t;
    if (r < n) {
        row_ptr[r] = gpos;
        dinv[r] = rsqrtf((float)(v + 1)); // +1 self loop; deg>=1 so clip no-op
    }
    if (r == n) row_ptr[n] = gpos;        // n = 50000 = 195*256+80 -> covered
    lcur[t] = gpos;
    __syncthreads();
    for (int i = s + t; i < e; i += 256) {
        unsigned rc = bkt[i];
        int pos = atomicAdd(&lcur[(rc >> 16) & 255], 1);
        cols16[pos] = (u16)(rc & 0xffffu);
    }
}

// ---------------- CSR SPMM: fp16 gather, batched-8 MLP, u16 cols + L2-hot dinv ----------------
// Y[i,:] = dinv[i] * ( dinv[i]*X[i,:] + sum_j dinv[c_j]*X[c_j,:] )  (+ bias)
template <bool OUT16, bool BIAS>
__global__ __launch_bounds__(256) void spmm_csr_h(const int* __restrict__ row_ptr,
                         const u16* __restrict__ cols16,
                         const f16* __restrict__ Xh, const float* __restrict__ dinv,
                         const float* __restrict__ bias,
                         float* __restrict__ Y, f16* __restrict__ Yh, int n) {
    int tid = blockIdx.x * blockDim.x + threadIdx.x;
    int i = tid >> 5;        // node
    int l = tid & 31;        // 4-elem slot (DIM/4 == 32)
    if (i >= n) return;
    const f16x4v* X4 = reinterpret_cast<const f16x4v*>(Xh);
    float di = dinv[i];
    f16x4v xv = X4[(size_t)i * 32 + l];
    float4 acc;   // acc = di*x_i + sum dinv_c*x_c ; scaled by di at the end
    acc.x = di * (float)xv[0]; acc.y = di * (float)xv[1];
    acc.z = di * (float)xv[2]; acc.w = di * (float)xv[3];
    int s = row_ptr[i], e = row_ptr[i + 1];
    for (int j = s; j < e; j += 8) {
        int c[8]; bool ok[8];
        #pragma unroll
        for (int t = 0; t < 8; ++t) {
            int idx = j + t;
            ok[t] = idx < e;
            c[t] = (int)cols16[ok[t] ? idx : (e - 1)];
        }
        f16x4v g[8];
        #pragma unroll
        for (int t = 0; t < 8; ++t) g[t] = X4[(size_t)c[t] * 32 + l];  // long-pole gathers
        float w[8];
        #pragma unroll
        for (int t = 0; t < 8; ++t) w[t] = ok[t] ? dinv[c[t]] : 0.f;   // L2-hot 200KB
        #pragma unroll
        for (int t = 0; t < 8; ++t) {
            acc.x += w[t] * (float)g[t][0];
            acc.y += w[t] * (float)g[t][1];
            acc.z += w[t] * (float)g[t][2];
            acc.w += w[t] * (float)g[t][3];
        }
    }
    acc.x *= di; acc.y *= di; acc.z *= di; acc.w *= di;
    if (BIAS) {
        float4 b = reinterpret_cast<const float4*>(bias)[l];
        acc.x += b.x; acc.y += b.y; acc.z += b.z; acc.w += b.w;
    }
    if (OUT16) {
        f16x4v o = { (f16)acc.x, (f16)acc.y, (f16)acc.z, (f16)acc.w };
        *reinterpret_cast<f16x4v*>(&Yh[(size_t)i * DIM + l * 4]) = o;
    } else {
        reinterpret_cast<float4*>(Y)[(size_t)i * 32 + l] = acc;
    }
}

// ---------------- fused MLP: z = (relu(y1 @ W1^T + b1)) @ W2^T, all f16 MFMA ----------------
// Barrier-free: each wave owns 32 rows end-to-end; h lives in wave-private LDS.
__global__ __launch_bounds__(256, 2) void mlp_fused(
        const f16* __restrict__ y1, const f16* __restrict__ w1,
        const float* __restrict__ b1, const f16* __restrict__ w2,
        f16* __restrict__ z, int M) {
    constexpr int HSTR = 264;                 // 256 + 8 pad: 16B-aligned rows
    __shared__ f16 hl[4][32][HSTR];           // 66 KB -> 2 blocks/CU
    const int wave = threadIdx.x >> 6;
    const int lane = threadIdx.x & 63;
    const int lr = lane & 15;                 // fragment row/col index
    const int lq = lane >> 4;                 // k-quad (8 elems)
    const int mbase = blockIdx.x * 128 + wave * 32;

    // y1 B-frags for this wave's 32 rows, all k=128: read once, reuse all quarters.
    f16x8 yb[2][4];
    #pragma unroll
    for (int nf = 0; nf < 2; ++nf) {
        int r = min(mbase + nf * 16 + lr, M - 1);
        const f16* pr = y1 + (size_t)r * 128 + lq * 8;
        #pragma unroll
        for (int ks = 0; ks < 4; ++ks)
            yb[nf][ks] = *reinterpret_cast<const f16x8*>(pr + ks * 32);
    }

    // ---- phase 1: h = relu(y1 W1^T + b1), 4 quarters of 64 h-cols ----
    #pragma unroll 1
    for (int q = 0; q < 4; ++q) {
        const int hc0 = q * 64;
        f16x8 wa[4][4];
        #pragma unroll
        for (int mf = 0; mf < 4; ++mf) {
            const f16* pw = w1 + (size_t)(hc0 + mf * 16 + lr) * 128 + lq * 8;
            #pragma unroll
            for (int ks = 0; ks < 4; ++ks)
                wa[mf][ks] = *reinterpret_cast<const f16x8*>(pw + ks * 32);
        }
        f32x4 acc[4][2] = {};
        #pragma unroll
        for (int ks = 0; ks < 4; ++ks)
            #pragma unroll
            for (int mf = 0; mf < 4; ++mf)
                #pragma unroll
                for (int nf = 0; nf < 2; ++nf)
                    acc[mf][nf] = MFMAH(wa[mf][ks], yb[nf][ks], acc[mf][nf]);
        #pragma unroll
        for (int mf = 0; mf < 4; ++mf) {
            float4 bb = *reinterpret_cast<const float4*>(&b1[hc0 + mf * 16 + lq * 4]);
            #pragma unroll
            for (int nf = 0; nf < 2; ++nf) {
                f16x4v hv = { (f16)fmaxf(acc[mf][nf][0] + bb.x, 0.f),
                              (f16)fmaxf(acc[mf][nf][1] + bb.y, 0.f),
                              (f16)fmaxf(acc[mf][nf][2] + bb.z, 0.f),
                              (f16)fmaxf(acc[mf][nf][3] + bb.w, 0.f) };
                *reinterpret_cast<f16x4v*>(&hl[wave][nf * 16 + lr][hc0 + mf * 16 + lq * 4]) = hv;
            }
        }
    }

    // ---- phase 2: z = h W2^T  (wave-private LDS reads; no barrier needed) ----
    f32x4 acc2[8][2] = {};
    #pragma unroll 1
    for (int ks = 0; ks < 8; ++ks) {
        f16x8 hb[2];
        #pragma unroll
        for (int nf = 0; nf < 2; ++nf)
            hb[nf] = *reinterpret_cast<const f16x8*>(&hl[wave][nf * 16 + lr][ks * 32 + lq * 8]);
        f16x8 wa2[8];
        #pragma unroll
        for (int mf = 0; mf < 8; ++mf)
            wa2[mf] = *reinterpret_cast<const f16x8*>(w2 + (size_t)(mf * 16 + lr) * 256 + ks * 32 + lq * 8);
        #pragma unroll
        for (int mf = 0; mf < 8; ++mf)
            #pragma unroll
            for (int nf = 0; nf < 2; ++nf)
                acc2[mf][nf] = MFMAH(wa2[mf], hb[nf], acc2[mf][nf]);
    }
    #pragma unroll
    for (int nf = 0; nf < 2; ++nf) {
        int node = mbase + nf * 16 + lr;
        if (node >= M) continue;
        #pragma unroll
        for (int mf = 0; mf < 8; ++mf) {
            f16x4v zv = { (f16)acc2[mf][nf][0], (f16)acc2[mf][nf][1],
                          (f16)acc2[mf][nf][2], (f16)acc2[mf][nf][3] };
            *reinterpret_cast<f16x4v*>(z + (size_t)node * 128 + mf * 16 + lq * 4) = zv;
        }
    }
}

extern "C" void kernel_launch(void* const* d_in, const int* in_sizes, int n_in,
                              void* d_out, int out_size, void* d_ws, size_t ws_size,
                              hipStream_t stream) {
    const float* x  = (const float*)d_in[0];
    const int*   ei = (const int*)d_in[1];
    const float* W1 = (const float*)d_in[2];
    const float* b1 = (const float*)d_in[3];
    const float* W2 = (const float*)d_in[4];
    const float* b2 = (const float*)d_in[5];
    float* out = (float*)d_out;

    const int N = NNODES;
    const int E = in_sizes[1] / 2;
    const int IN_D = 128, HID = 256;
    const int* row = ei;
    const int* col = ei + E;

    // workspace carve-out (aligned to 256B)
    char* ws = (char*)d_ws;
    size_t off = 0;
    auto carve = [&](size_t bytes) { void* p = ws + off; off += (bytes + 255) & ~size_t(255); return p; };
    int*      bcnt    = (int*)carve((size_t)256 * 4);
    int*      bbase   = (int*)carve((size_t)(NBUCK + 1) * 4);
    int*      gcursor = (int*)carve((size_t)256 * 4);
    int*      row_ptr = (int*)carve((size_t)(N + 1) * 4);
    float*    dinv    = (float*)carve((size_t)N * 4);
    unsigned* bkt     = (unsigned*)carve((size_t)E * 4);   // packed (row<<16|col)
    u16*      cols16  = (u16*)carve((size_t)E * 2);
    f16*      w1h     = (f16*)carve((size_t)HID * IN_D * 2);
    f16*      w2h     = (f16*)carve((size_t)IN_D * HID * 2);
    f16*      xh      = (f16*)carve((size_t)N * IN_D * 2); // 12.8 MB
    f16*      y1h     = (f16*)carve((size_t)N * IN_D * 2); // 12.8 MB, becomes z in-place
    f16*      zh      = y1h;

    const int TB = 256;
    const int eblk = (E + 2047) / 2048;   // 391

    // 1) bucketed CSR build (no global deg pass, no random full-range scatter)
    hipMemsetAsync(bcnt, 0, 256 * 4, stream);
    bucket_hist<<<eblk, TB, 0, stream>>>(row, bcnt, E);
    bucket_scan<<<1, TB, 0, stream>>>(bcnt, bbase, gcursor, NBUCK);
    bucket_place<<<eblk, TB, 0, stream>>>(row, col, gcursor, bkt, E);
    csr_fill<<<NBUCK, TB, 0, stream>>>(bkt, bbase, row_ptr, dinv, cols16, N);

    // f16 conversions (independent)
    f32_to_f16<<<((HID * IN_D / 4) + TB - 1) / TB, TB, 0, stream>>>(W1, w1h, HID * IN_D / 4);
    f32_to_f16<<<((IN_D * HID / 4) + TB - 1) / TB, TB, 0, stream>>>(W2, w2h, IN_D * HID / 4);
    f32_to_f16<<<((N * IN_D / 4) + TB - 1) / TB, TB, 0, stream>>>(x, xh, N * IN_D / 4);

    // 2) y1 = A' x   (fp16 gather -> fp16 out)
    spmm_csr_h<true, false><<<(N * 32 + TB - 1) / TB, TB, 0, stream>>>(
        row_ptr, cols16, xh, dinv, nullptr, nullptr, y1h, N);

    // 3+4) z = relu(y1 W1^T + b1) W2^T   (fused, z in-place over y1)
    mlp_fused<<<(N + 127) / 128, 256, 0, stream>>>(y1h, w1h, b1, w2h, zh, N);

    // 5) out = A' z + b2   (fp16 gather -> fp32 out)
    spmm_csr_h<false, true><<<(N * 32 + TB - 1) / TB, TB, 0, stream>>>(
        row_ptr, cols16, zh, dinv, b2, out, nullptr, N);
}

// Round 9
// 156.612 us; speedup vs baseline: 18.3009x; 1.0166x over previous
//
#include <hip/hip_runtime.h>
#include <hip/hip_bf16.h>

#define NNODES 50000   // must stay < 65536 (row/col packed into one u32)
#define DIM 128        // both SPMMs run on 128 dims after the W2 reorder
#define NBUCK 196      // ceil(NNODES/256); bucket b covers rows [b*256, b*256+256)

typedef unsigned short u16;
typedef _Float16 f16;
typedef float  f32x4  __attribute__((ext_vector_type(4)));
typedef _Float16 f16x4v __attribute__((ext_vector_type(4)));
typedef _Float16 f16x8 __attribute__((ext_vector_type(8)));

#define MFMAH(a, b, c) __builtin_amdgcn_mfma_f32_16x16x32_f16((a), (b), (c), 0, 0, 0)

// ---------------- zero 256 ints (replaces 43us fillBuffer blit) ----------------
__global__ void zero256(int* __restrict__ p) {
    p[threadIdx.x] = 0;
}

// ---------------- fp32 -> fp16 convert (vectorized x4, two buffers) ----------------
__global__ void f32_to_f16_2(const float* __restrict__ inA, f16* __restrict__ outA, int n4A,
                             const float* __restrict__ inB, f16* __restrict__ outB, int n4B) {
    int i = blockIdx.x * blockDim.x + threadIdx.x;
    if (i < n4A) {
        float4 v = reinterpret_cast<const float4*>(inA)[i];
        f16x4v o = { (f16)v.x, (f16)v.y, (f16)v.z, (f16)v.w };
        reinterpret_cast<f16x4v*>(outA)[i] = o;
    }
    int jb = i - n4A;
    if (jb >= 0 && jb < n4B) {
        float4 v = reinterpret_cast<const float4*>(inB)[jb];
        f16x4v o = { (f16)v.x, (f16)v.y, (f16)v.z, (f16)v.w };
        reinterpret_cast<f16x4v*>(outB)[jb] = o;
    }
}

__global__ void f32_to_f16(const float* __restrict__ in, f16* __restrict__ out, int n4) {
    int i = blockIdx.x * blockDim.x + threadIdx.x;
    if (i < n4) {
        float4 v = reinterpret_cast<const float4*>(in)[i];
        f16x4v o = { (f16)v.x, (f16)v.y, (f16)v.z, (f16)v.w };
        reinterpret_cast<f16x4v*>(out)[i] = o;
    }
}

// ---------------- pass A: per-bucket histogram (LDS -> global atomics) ----------------
__global__ __launch_bounds__(256) void bucket_hist(const int* __restrict__ row,
                                                   int* __restrict__ bcnt, int nE) {
    __shared__ int hist[256];
    int t = threadIdx.x;
    hist[t] = 0;
    __syncthreads();
    int base_e = blockIdx.x * 2048 + t;
    #pragma unroll
    for (int k = 0; k < 8; ++k) {
        int e = base_e + k * 256;
        if (e < nE) atomicAdd(&hist[(unsigned)row[e] >> 8], 1);
    }
    __syncthreads();
    if (hist[t] > 0) atomicAdd(&bcnt[t], hist[t]);
}

// ---------------- bucket exclusive scan -> bbase[NB+1], gcursor ----------------
__global__ __launch_bounds__(256) void bucket_scan(const int* __restrict__ bcnt,
                                                   int* __restrict__ bbase,
                                                   int* __restrict__ gcursor, int nb) {
    __shared__ int sc[256];
    int t = threadIdx.x;
    int v = (t < nb) ? bcnt[t] : 0;
    sc[t] = v;
    __syncthreads();
    for (int off = 1; off < 256; off <<= 1) {
        int u = (t >= off) ? sc[t - off] : 0;
        __syncthreads();
        sc[t] += u;
        __syncthreads();
    }
    if (t < nb) {
        int excl = sc[t] - v;
        bbase[t] = excl;
        gcursor[t] = excl;
    }
    if (t == 255) bbase[nb] = sc[255];   // total == E
}

// ---------------- pass B: place packed (row,col) edges grouped by bucket ----------------
// Per-(block,bucket) runs are contiguous -> ~80B store runs instead of random 4B.
__global__ __launch_bounds__(256) void bucket_place(const int* __restrict__ row,
                                                    const int* __restrict__ col,
                                                    int* __restrict__ gcursor,
                                                    unsigned* __restrict__ bkt, int nE) {
    __shared__ int hist[256];
    __shared__ int cur[256];
    int t = threadIdx.x;
    hist[t] = 0;
    __syncthreads();
    unsigned pk[8]; int valid = 0;
    int base_e = blockIdx.x * 2048 + t;
    #pragma unroll
    for (int k = 0; k < 8; ++k) {
        int e = base_e + k * 256;
        if (e < nE) {
            unsigned r = (unsigned)row[e], c = (unsigned)col[e];
            pk[k] = (r << 16) | c;
            valid |= 1 << k;
            atomicAdd(&hist[r >> 8], 1);
        }
    }
    __syncthreads();
    if (hist[t] > 0) cur[t] = atomicAdd(&gcursor[t], hist[t]);
    __syncthreads();
    #pragma unroll
    for (int k = 0; k < 8; ++k) {
        if (valid & (1 << k)) {
            int pos = atomicAdd(&cur[pk[k] >> 24], 1);   // pk>>24 == row>>8
            bkt[pos] = pk[k];
        }
    }
}

// ---------------- pass C: one block per bucket -> row_ptr, dinv, cols16 ----------------
__global__ __launch_bounds__(256) void csr_fill(const unsigned* __restrict__ bkt,
                                                const int* __restrict__ bbase,
                                                int* __restrict__ row_ptr,
                                                float* __restrict__ dinv,
                                                u16* __restrict__ cols16, int n) {
    __shared__ int lcnt[256], lscan[256], lcur[256];
    int b = blockIdx.x, t = threadIdx.x;
    int r0 = b << 8;
    int s = bbase[b], e = bbase[b + 1];
    lcnt[t] = 0;
    __syncthreads();
    for (int i = s + t; i < e; i += 256)
        atomicAdd(&lcnt[(bkt[i] >> 16) & 255], 1);
    __syncthreads();
    int v = lcnt[t];
    lscan[t] = v;
    __syncthreads();
    for (int off = 1; off < 256; off <<= 1) {
        int u = (t >= off) ? lscan[t - off] : 0;
        __syncthreads();
        lscan[t] += u;
        __syncthreads();
    }
    int gpos = s + lscan[t] - v;          // exclusive
    int r = r0 + t;
    if (r < n) {
        row_ptr[r] = gpos;
        dinv[r] = rsqrtf((float)(v + 1)); // +1 self loop; deg>=1 so clip no-op
    }
    if (r == n) row_ptr[n] = gpos;        // n = 50000 = 195*256+80 -> covered
    lcur[t] = gpos;
    __syncthreads();
    for (int i = s + t; i < e; i += 256) {
        unsigned rc = bkt[i];
        int pos = atomicAdd(&lcur[(rc >> 16) & 255], 1);
        cols16[pos] = (u16)(rc & 0xffffu);
    }
}

// ---------------- CSR SPMM: fp16 gather, batched-8 MLP, u16 cols + L2-hot dinv ----------------
// Y[i,:] = dinv[i] * ( dinv[i]*X[i,:] + sum_j dinv[c_j]*X[c_j,:] )  (+ bias)
template <bool OUT16, bool BIAS>
__global__ __launch_bounds__(256) void spmm_csr_h(const int* __restrict__ row_ptr,
                         const u16* __restrict__ cols16,
                         const f16* __restrict__ Xh, const float* __restrict__ dinv,
                         const float* __restrict__ bias,
                         float* __restrict__ Y, f16* __restrict__ Yh, int n) {
    int tid = blockIdx.x * blockDim.x + threadIdx.x;
    int i = tid >> 5;        // node
    int l = tid & 31;        // 4-elem slot (DIM/4 == 32)
    if (i >= n) return;
    const f16x4v* X4 = reinterpret_cast<const f16x4v*>(Xh);
    float di = dinv[i];
    f16x4v xv = X4[(size_t)i * 32 + l];
    float4 acc;   // acc = di*x_i + sum dinv_c*x_c ; scaled by di at the end
    acc.x = di * (float)xv[0]; acc.y = di * (float)xv[1];
    acc.z = di * (float)xv[2]; acc.w = di * (float)xv[3];
    int s = row_ptr[i], e = row_ptr[i + 1];
    for (int j = s; j < e; j += 8) {
        int c[8]; bool ok[8];
        #pragma unroll
        for (int t = 0; t < 8; ++t) {
            int idx = j + t;
            ok[t] = idx < e;
            c[t] = (int)cols16[ok[t] ? idx : (e - 1)];
        }
        f16x4v g[8];
        #pragma unroll
        for (int t = 0; t < 8; ++t) g[t] = X4[(size_t)c[t] * 32 + l];  // long-pole gathers
        float w[8];
        #pragma unroll
        for (int t = 0; t < 8; ++t) w[t] = ok[t] ? dinv[c[t]] : 0.f;   // L2-hot 200KB
        #pragma unroll
        for (int t = 0; t < 8; ++t) {
            acc.x += w[t] * (float)g[t][0];
            acc.y += w[t] * (float)g[t][1];
            acc.z += w[t] * (float)g[t][2];
            acc.w += w[t] * (float)g[t][3];
        }
    }
    acc.x *= di; acc.y *= di; acc.z *= di; acc.w *= di;
    if (BIAS) {
        float4 b = reinterpret_cast<const float4*>(bias)[l];
        acc.x += b.x; acc.y += b.y; acc.z += b.z; acc.w += b.w;
    }
    if (OUT16) {
        f16x4v o = { (f16)acc.x, (f16)acc.y, (f16)acc.z, (f16)acc.w };
        *reinterpret_cast<f16x4v*>(&Yh[(size_t)i * DIM + l * 4]) = o;
    } else {
        reinterpret_cast<float4*>(Y)[(size_t)i * 32 + l] = acc;
    }
}

// ---------------- fused MLP: z = (relu(y1 @ W1^T + b1)) @ W2^T, all f16 MFMA ----------------
// Barrier-free: each wave owns 32 rows end-to-end; h lives in wave-private LDS.
__global__ __launch_bounds__(256, 2) void mlp_fused(
        const f16* __restrict__ y1, const f16* __restrict__ w1,
        const float* __restrict__ b1, const f16* __restrict__ w2,
        f16* __restrict__ z, int M) {
    constexpr int HSTR = 264;                 // 256 + 8 pad: 16B-aligned rows
    __shared__ f16 hl[4][32][HSTR];           // 66 KB -> 2 blocks/CU
    const int wave = threadIdx.x >> 6;
    const int lane = threadIdx.x & 63;
    const int lr = lane & 15;                 // fragment row/col index
    const int lq = lane >> 4;                 // k-quad (8 elems)
    const int mbase = blockIdx.x * 128 + wave * 32;

    // y1 B-frags for this wave's 32 rows, all k=128: read once, reuse all quarters.
    f16x8 yb[2][4];
    #pragma unroll
    for (int nf = 0; nf < 2; ++nf) {
        int r = min(mbase + nf * 16 + lr, M - 1);
        const f16* pr = y1 + (size_t)r * 128 + lq * 8;
        #pragma unroll
        for (int ks = 0; ks < 4; ++ks)
            yb[nf][ks] = *reinterpret_cast<const f16x8*>(pr + ks * 32);
    }

    // ---- phase 1: h = relu(y1 W1^T + b1), 4 quarters of 64 h-cols ----
    #pragma unroll 1
    for (int q = 0; q < 4; ++q) {
        const int hc0 = q * 64;
        f16x8 wa[4][4];
        #pragma unroll
        for (int mf = 0; mf < 4; ++mf) {
            const f16* pw = w1 + (size_t)(hc0 + mf * 16 + lr) * 128 + lq * 8;
            #pragma unroll
            for (int ks = 0; ks < 4; ++ks)
                wa[mf][ks] = *reinterpret_cast<const f16x8*>(pw + ks * 32);
        }
        f32x4 acc[4][2] = {};
        #pragma unroll
        for (int ks = 0; ks < 4; ++ks)
            #pragma unroll
            for (int mf = 0; mf < 4; ++mf)
                #pragma unroll
                for (int nf = 0; nf < 2; ++nf)
                    acc[mf][nf] = MFMAH(wa[mf][ks], yb[nf][ks], acc[mf][nf]);
        #pragma unroll
        for (int mf = 0; mf < 4; ++mf) {
            float4 bb = *reinterpret_cast<const float4*>(&b1[hc0 + mf * 16 + lq * 4]);
            #pragma unroll
            for (int nf = 0; nf < 2; ++nf) {
                f16x4v hv = { (f16)fmaxf(acc[mf][nf][0] + bb.x, 0.f),
                              (f16)fmaxf(acc[mf][nf][1] + bb.y, 0.f),
                              (f16)fmaxf(acc[mf][nf][2] + bb.z, 0.f),
                              (f16)fmaxf(acc[mf][nf][3] + bb.w, 0.f) };
                *reinterpret_cast<f16x4v*>(&hl[wave][nf * 16 + lr][hc0 + mf * 16 + lq * 4]) = hv;
            }
        }
    }

    // ---- phase 2: z = h W2^T  (wave-private LDS reads; no barrier needed) ----
    f32x4 acc2[8][2] = {};
    #pragma unroll 1
    for (int ks = 0; ks < 8; ++ks) {
        f16x8 hb[2];
        #pragma unroll
        for (int nf = 0; nf < 2; ++nf)
            hb[nf] = *reinterpret_cast<const f16x8*>(&hl[wave][nf * 16 + lr][ks * 32 + lq * 8]);
        f16x8 wa2[8];
        #pragma unroll
        for (int mf = 0; mf < 8; ++mf)
            wa2[mf] = *reinterpret_cast<const f16x8*>(w2 + (size_t)(mf * 16 + lr) * 256 + ks * 32 + lq * 8);
        #pragma unroll
        for (int mf = 0; mf < 8; ++mf)
            #pragma unroll
            for (int nf = 0; nf < 2; ++nf)
                acc2[mf][nf] = MFMAH(wa2[mf], hb[nf], acc2[mf][nf]);
    }
    #pragma unroll
    for (int nf = 0; nf < 2; ++nf) {
        int node = mbase + nf * 16 + lr;
        if (node >= M) continue;
        #pragma unroll
        for (int mf = 0; mf < 8; ++mf) {
            f16x4v zv = { (f16)acc2[mf][nf][0], (f16)acc2[mf][nf][1],
                          (f16)acc2[mf][nf][2], (f16)acc2[mf][nf][3] };
            *reinterpret_cast<f16x4v*>(z + (size_t)node * 128 + mf * 16 + lq * 4) = zv;
        }
    }
}

extern "C" void kernel_launch(void* const* d_in, const int* in_sizes, int n_in,
                              void* d_out, int out_size, void* d_ws, size_t ws_size,
                              hipStream_t stream) {
    const float* x  = (const float*)d_in[0];
    const int*   ei = (const int*)d_in[1];
    const float* W1 = (const float*)d_in[2];
    const float* b1 = (const float*)d_in[3];
    const float* W2 = (const float*)d_in[4];
    const float* b2 = (const float*)d_in[5];
    float* out = (float*)d_out;

    const int N = NNODES;
    const int E = in_sizes[1] / 2;
    const int IN_D = 128, HID = 256;
    const int* row = ei;
    const int* col = ei + E;

    // workspace carve-out (aligned to 256B)
    char* ws = (char*)d_ws;
    size_t off = 0;
    auto carve = [&](size_t bytes) { void* p = ws + off; off += (bytes + 255) & ~size_t(255); return p; };
    int*      bcnt    = (int*)carve((size_t)256 * 4);
    int*      bbase   = (int*)carve((size_t)(NBUCK + 1) * 4);
    int*      gcursor = (int*)carve((size_t)256 * 4);
    int*      row_ptr = (int*)carve((size_t)(N + 1) * 4);
    float*    dinv    = (float*)carve((size_t)N * 4);
    unsigned* bkt     = (unsigned*)carve((size_t)E * 4);   // packed (row<<16|col)
    u16*      cols16  = (u16*)carve((size_t)E * 2);
    f16*      w1h     = (f16*)carve((size_t)HID * IN_D * 2);
    f16*      w2h     = (f16*)carve((size_t)IN_D * HID * 2);
    f16*      xh      = (f16*)carve((size_t)N * IN_D * 2); // 12.8 MB
    f16*      y1h     = (f16*)carve((size_t)N * IN_D * 2); // 12.8 MB, becomes z in-place
    f16*      zh      = y1h;

    const int TB = 256;
    const int eblk = (E + 2047) / 2048;   // 391

    // 1) bucketed CSR build (no global deg pass, no random full-range scatter)
    zero256<<<1, 256, 0, stream>>>(bcnt);
    bucket_hist<<<eblk, TB, 0, stream>>>(row, bcnt, E);
    bucket_scan<<<1, TB, 0, stream>>>(bcnt, bbase, gcursor, NBUCK);
    bucket_place<<<eblk, TB, 0, stream>>>(row, col, gcursor, bkt, E);
    csr_fill<<<NBUCK, TB, 0, stream>>>(bkt, bbase, row_ptr, dinv, cols16, N);

    // f16 conversions (weights fused into one launch; x separate)
    f32_to_f16_2<<<((HID * IN_D / 4) * 2 + TB - 1) / TB, TB, 0, stream>>>(
        W1, w1h, HID * IN_D / 4, W2, w2h, IN_D * HID / 4);
    f32_to_f16<<<((N * IN_D / 4) + TB - 1) / TB, TB, 0, stream>>>(x, xh, N * IN_D / 4);

    // 2) y1 = A' x   (fp16 gather -> fp16 out)
    spmm_csr_h<true, false><<<(N * 32 + TB - 1) / TB, TB, 0, stream>>>(
        row_ptr, cols16, xh, dinv, nullptr, nullptr, y1h, N);

    // 3+4) z = relu(y1 W1^T + b1) W2^T   (fused, z in-place over y1)
    mlp_fused<<<(N + 127) / 128, 256, 0, stream>>>(y1h, w1h, b1, w2h, zh, N);

    // 5) out = A' z + b2   (fp16 gather -> fp32 out)
    spmm_csr_h<false, true><<<(N * 32 + TB - 1) / TB, TB, 0, stream>>>(
        row_ptr, cols16, zh, dinv, b2, out, nullptr, N);
}

// Round 10
// 155.417 us; speedup vs baseline: 18.4416x; 1.0077x over previous
//
#include <hip/hip_runtime.h>
#include <hip/hip_bf16.h>

#define NNODES 50000   // must stay < 65536 (row/col packed into one u32)
#define DIM 128        // both SPMMs run on 128 dims after the W2 reorder
#define NBUCK 196      // ceil(NNODES/256); bucket b covers rows [b*256, b*256+256)

typedef unsigned short u16;
typedef _Float16 f16;
typedef float  f32x4  __attribute__((ext_vector_type(4)));
typedef _Float16 f16x4v __attribute__((ext_vector_type(4)));
typedef _Float16 f16x8 __attribute__((ext_vector_type(8)));

#define MFMAH(a, b, c) __builtin_amdgcn_mfma_f32_16x16x32_f16((a), (b), (c), 0, 0, 0)

// ---------------- zero 256 ints ----------------
__global__ void zero256(int* __restrict__ p) {
    p[threadIdx.x] = 0;
}

// ---------------- pass A: per-bucket histogram (LDS -> global atomics) ----------------
__global__ __launch_bounds__(256) void bucket_hist(const int* __restrict__ row,
                                                   int* __restrict__ bcnt, int nE) {
    __shared__ int hist[256];
    int t = threadIdx.x;
    hist[t] = 0;
    __syncthreads();
    int base_e = blockIdx.x * 2048 + t;
    #pragma unroll
    for (int k = 0; k < 8; ++k) {
        int e = base_e + k * 256;
        if (e < nE) atomicAdd(&hist[(unsigned)row[e] >> 8], 1);
    }
    __syncthreads();
    if (hist[t] > 0) atomicAdd(&bcnt[t], hist[t]);
}

// ---------------- bucket exclusive scan -> bbase[NB+1], gcursor ----------------
__global__ __launch_bounds__(256) void bucket_scan(const int* __restrict__ bcnt,
                                                   int* __restrict__ bbase,
                                                   int* __restrict__ gcursor, int nb) {
    __shared__ int sc[256];
    int t = threadIdx.x;
    int v = (t < nb) ? bcnt[t] : 0;
    sc[t] = v;
    __syncthreads();
    for (int off = 1; off < 256; off <<= 1) {
        int u = (t >= off) ? sc[t - off] : 0;
        __syncthreads();
        sc[t] += u;
        __syncthreads();
    }
    if (t < nb) {
        int excl = sc[t] - v;
        bbase[t] = excl;
        gcursor[t] = excl;
    }
    if (t == 255) bbase[nb] = sc[255];   // total == E
}

// ---------------- pass B: place packed (row,col) edges grouped by bucket ----------------
__global__ __launch_bounds__(256) void bucket_place(const int* __restrict__ row,
                                                    const int* __restrict__ col,
                                                    int* __restrict__ gcursor,
                                                    unsigned* __restrict__ bkt, int nE) {
    __shared__ int hist[256];
    __shared__ int cur[256];
    int t = threadIdx.x;
    hist[t] = 0;
    __syncthreads();
    unsigned pk[8]; int valid = 0;
    int base_e = blockIdx.x * 2048 + t;
    #pragma unroll
    for (int k = 0; k < 8; ++k) {
        int e = base_e + k * 256;
        if (e < nE) {
            unsigned r = (unsigned)row[e], c = (unsigned)col[e];
            pk[k] = (r << 16) | c;
            valid |= 1 << k;
            atomicAdd(&hist[r >> 8], 1);
        }
    }
    __syncthreads();
    if (hist[t] > 0) cur[t] = atomicAdd(&gcursor[t], hist[t]);
    __syncthreads();
    #pragma unroll
    for (int k = 0; k < 8; ++k) {
        if (valid & (1 << k)) {
            int pos = atomicAdd(&cur[pk[k] >> 24], 1);   // pk>>24 == row>>8
            bkt[pos] = pk[k];
        }
    }
}

// ---------------- pass C: one block per bucket -> row_ptr, dinv, cols16 ----------------
__global__ __launch_bounds__(256) void csr_fill(const unsigned* __restrict__ bkt,
                                                const int* __restrict__ bbase,
                                                int* __restrict__ row_ptr,
                                                float* __restrict__ dinv,
                                                u16* __restrict__ cols16, int n) {
    __shared__ int lcnt[256], lscan[256], lcur[256];
    int b = blockIdx.x, t = threadIdx.x;
    int r0 = b << 8;
    int s = bbase[b], e = bbase[b + 1];
    lcnt[t] = 0;
    __syncthreads();
    for (int i = s + t; i < e; i += 256)
        atomicAdd(&lcnt[(bkt[i] >> 16) & 255], 1);
    __syncthreads();
    int v = lcnt[t];
    lscan[t] = v;
    __syncthreads();
    for (int off = 1; off < 256; off <<= 1) {
        int u = (t >= off) ? lscan[t - off] : 0;
        __syncthreads();
        lscan[t] += u;
        __syncthreads();
    }
    int gpos = s + lscan[t] - v;          // exclusive
    int r = r0 + t;
    if (r < n) {
        row_ptr[r] = gpos;
        dinv[r] = rsqrtf((float)(v + 1)); // +1 self loop; deg>=1 so clip no-op
    }
    if (r == n) row_ptr[n] = gpos;        // n = 50000 = 195*256+80 -> covered
    lcur[t] = gpos;
    __syncthreads();
    for (int i = s + t; i < e; i += 256) {
        unsigned rc = bkt[i];
        int pos = atomicAdd(&lcur[(rc >> 16) & 255], 1);
        cols16[pos] = (u16)(rc & 0xffffu);
    }
}

// ---------------- prep: W1/W2 -> f16, xs = dinv*x (f16), zero rows N of xs/zs ----------------
// One launch replaces two conversion kernels; runs after csr_fill (needs dinv).
__global__ __launch_bounds__(256) void prep_tables(
        const float* __restrict__ W1, const float* __restrict__ W2,
        const float* __restrict__ x, const float* __restrict__ dinv,
        f16* __restrict__ w1h, f16* __restrict__ w2h,
        f16* __restrict__ xs, f16* __restrict__ zs, int n) {
    const int WQ = (256 * 128) / 4;       // 8192 quads per weight
    const int XQ = n * (DIM / 4);         // node-feature quads
    int i = blockIdx.x * 256 + threadIdx.x;
    if (i < WQ) {
        float4 v = reinterpret_cast<const float4*>(W1)[i];
        f16x4v o = { (f16)v.x, (f16)v.y, (f16)v.z, (f16)v.w };
        reinterpret_cast<f16x4v*>(w1h)[i] = o;
    } else if (i < 2 * WQ) {
        int j = i - WQ;
        float4 v = reinterpret_cast<const float4*>(W2)[j];
        f16x4v o = { (f16)v.x, (f16)v.y, (f16)v.z, (f16)v.w };
        reinterpret_cast<f16x4v*>(w2h)[j] = o;
    } else {
        int j = i - 2 * WQ;
        if (j < XQ) {
            float d = dinv[j >> 5];
            float4 v = reinterpret_cast<const float4*>(x)[j];
            f16x4v o = { (f16)(d * v.x), (f16)(d * v.y), (f16)(d * v.z), (f16)(d * v.w) };
            reinterpret_cast<f16x4v*>(xs)[j] = o;
        } else if (j < XQ + 32) {          // zero row N of xs (gather tail target)
            f16x4v o = {};
            reinterpret_cast<f16x4v*>(xs)[j] = o;
        } else if (j < XQ + 64) {          // zero row N of zs
            f16x4v o = {};
            reinterpret_cast<f16x4v*>(zs)[XQ + (j - XQ - 32)] = o;
        }
    }
}

// ---------------- CSR SPMM: pre-scaled f16 gather, batched-16, zero-row tail ----------------
// Y[i,:] = dinv[i] * ( Xs[i,:] + sum_j Xs[c_j,:] )  (+ bias)   where Xs = dinv (.) X
template <bool OUT16, bool BIAS>
__global__ __launch_bounds__(256) void spmm_gather(const int* __restrict__ row_ptr,
                         const u16* __restrict__ cols16,
                         const f16* __restrict__ Xs, const float* __restrict__ dinv,
                         const float* __restrict__ bias,
                         float* __restrict__ Y, f16* __restrict__ Yh, int n) {
    int tid = blockIdx.x * blockDim.x + threadIdx.x;
    int i = tid >> 5;        // node
    int l = tid & 31;        // 4-elem slot (DIM/4 == 32)
    if (i >= n) return;
    const f16x4v* X4 = reinterpret_cast<const f16x4v*>(Xs);
    float di = dinv[i];
    f16x4v xv = X4[(size_t)i * 32 + l];           // self term (pre-scaled)
    float4 acc;
    acc.x = (float)xv[0]; acc.y = (float)xv[1];
    acc.z = (float)xv[2]; acc.w = (float)xv[3];
    int s = row_ptr[i], e = row_ptr[i + 1];
    for (int j = s; j < e; j += 16) {
        int c[16];
        #pragma unroll
        for (int t = 0; t < 16; ++t) {
            int idx = j + t;
            bool ok = idx < e;
            int cc = (int)cols16[ok ? idx : (e - 1)];
            c[t] = ok ? cc : n;                   // invalid -> zero row N
        }
        f16x4v g[16];
        #pragma unroll
        for (int t = 0; t < 16; ++t) g[t] = X4[(size_t)c[t] * 32 + l];  // 32 in flight/wave
        #pragma unroll
        for (int t = 0; t < 16; ++t) {
            acc.x += (float)g[t][0];
            acc.y += (float)g[t][1];
            acc.z += (float)g[t][2];
            acc.w += (float)g[t][3];
        }
    }
    acc.x *= di; acc.y *= di; acc.z *= di; acc.w *= di;
    if (BIAS) {
        float4 b = reinterpret_cast<const float4*>(bias)[l];
        acc.x += b.x; acc.y += b.y; acc.z += b.z; acc.w += b.w;
    }
    if (OUT16) {
        f16x4v o = { (f16)acc.x, (f16)acc.y, (f16)acc.z, (f16)acc.w };
        *reinterpret_cast<f16x4v*>(&Yh[(size_t)i * DIM + l * 4]) = o;
    } else {
        reinterpret_cast<float4*>(Y)[(size_t)i * 32 + l] = acc;
    }
}

// ---------------- fused MLP: zs = dinv (.) [ relu(y1 W1^T + b1) W2^T ], all f16 MFMA ----------------
// Barrier-free: each wave owns 32 rows end-to-end; h lives in wave-private LDS.
// Epilogue pre-scales by dinv so SPMM2's gather table needs no per-neighbor weight.
__global__ __launch_bounds__(256, 2) void mlp_fused(
        const f16* __restrict__ y1, const f16* __restrict__ w1,
        const float* __restrict__ b1, const f16* __restrict__ w2,
        const float* __restrict__ dinv, f16* __restrict__ zs, int M) {
    constexpr int HSTR = 264;                 // 256 + 8 pad: 16B-aligned rows
    __shared__ f16 hl[4][32][HSTR];           // 66 KB -> 2 blocks/CU
    const int wave = threadIdx.x >> 6;
    const int lane = threadIdx.x & 63;
    const int lr = lane & 15;                 // fragment row/col index
    const int lq = lane >> 4;                 // k-quad (8 elems)
    const int mbase = blockIdx.x * 128 + wave * 32;

    // y1 B-frags for this wave's 32 rows, all k=128: read once, reuse all quarters.
    f16x8 yb[2][4];
    #pragma unroll
    for (int nf = 0; nf < 2; ++nf) {
        int r = min(mbase + nf * 16 + lr, M - 1);
        const f16* pr = y1 + (size_t)r * 128 + lq * 8;
        #pragma unroll
        for (int ks = 0; ks < 4; ++ks)
            yb[nf][ks] = *reinterpret_cast<const f16x8*>(pr + ks * 32);
    }

    // ---- phase 1: h = relu(y1 W1^T + b1), 4 quarters of 64 h-cols ----
    #pragma unroll 1
    for (int q = 0; q < 4; ++q) {
        const int hc0 = q * 64;
        f16x8 wa[4][4];
        #pragma unroll
        for (int mf = 0; mf < 4; ++mf) {
            const f16* pw = w1 + (size_t)(hc0 + mf * 16 + lr) * 128 + lq * 8;
            #pragma unroll
            for (int ks = 0; ks < 4; ++ks)
                wa[mf][ks] = *reinterpret_cast<const f16x8*>(pw + ks * 32);
        }
        f32x4 acc[4][2] = {};
        #pragma unroll
        for (int ks = 0; ks < 4; ++ks)
            #pragma unroll
            for (int mf = 0; mf < 4; ++mf)
                #pragma unroll
                for (int nf = 0; nf < 2; ++nf)
                    acc[mf][nf] = MFMAH(wa[mf][ks], yb[nf][ks], acc[mf][nf]);
        #pragma unroll
        for (int mf = 0; mf < 4; ++mf) {
            float4 bb = *reinterpret_cast<const float4*>(&b1[hc0 + mf * 16 + lq * 4]);
            #pragma unroll
            for (int nf = 0; nf < 2; ++nf) {
                f16x4v hv = { (f16)fmaxf(acc[mf][nf][0] + bb.x, 0.f),
                              (f16)fmaxf(acc[mf][nf][1] + bb.y, 0.f),
                              (f16)fmaxf(acc[mf][nf][2] + bb.z, 0.f),
                              (f16)fmaxf(acc[mf][nf][3] + bb.w, 0.f) };
                *reinterpret_cast<f16x4v*>(&hl[wave][nf * 16 + lr][hc0 + mf * 16 + lq * 4]) = hv;
            }
        }
    }

    // ---- phase 2: z = h W2^T  (wave-private LDS reads; no barrier needed) ----
    f32x4 acc2[8][2] = {};
    #pragma unroll 1
    for (int ks = 0; ks < 8; ++ks) {
        f16x8 hb[2];
        #pragma unroll
        for (int nf = 0; nf < 2; ++nf)
            hb[nf] = *reinterpret_cast<const f16x8*>(&hl[wave][nf * 16 + lr][ks * 32 + lq * 8]);
        f16x8 wa2[8];
        #pragma unroll
        for (int mf = 0; mf < 8; ++mf)
            wa2[mf] = *reinterpret_cast<const f16x8*>(w2 + (size_t)(mf * 16 + lr) * 256 + ks * 32 + lq * 8);
        #pragma unroll
        for (int mf = 0; mf < 8; ++mf)
            #pragma unroll
            for (int nf = 0; nf < 2; ++nf)
                acc2[mf][nf] = MFMAH(wa2[mf], hb[nf], acc2[mf][nf]);
    }
    #pragma unroll
    for (int nf = 0; nf < 2; ++nf) {
        int node = mbase + nf * 16 + lr;
        if (node >= M) continue;
        float dn = dinv[node];
        #pragma unroll
        for (int mf = 0; mf < 8; ++mf) {
            f16x4v zv = { (f16)(dn * acc2[mf][nf][0]), (f16)(dn * acc2[mf][nf][1]),
                          (f16)(dn * acc2[mf][nf][2]), (f16)(dn * acc2[mf][nf][3]) };
            *reinterpret_cast<f16x4v*>(zs + (size_t)node * 128 + mf * 16 + lq * 4) = zv;
        }
    }
}

extern "C" void kernel_launch(void* const* d_in, const int* in_sizes, int n_in,
                              void* d_out, int out_size, void* d_ws, size_t ws_size,
                              hipStream_t stream) {
    const float* x  = (const float*)d_in[0];
    const int*   ei = (const int*)d_in[1];
    const float* W1 = (const float*)d_in[2];
    const float* b1 = (const float*)d_in[3];
    const float* W2 = (const float*)d_in[4];
    const float* b2 = (const float*)d_in[5];
    float* out = (float*)d_out;

    const int N = NNODES;
    const int E = in_sizes[1] / 2;
    const int IN_D = 128, HID = 256;
    const int* row = ei;
    const int* col = ei + E;

    // workspace carve-out (aligned to 256B)
    char* ws = (char*)d_ws;
    size_t off = 0;
    auto carve = [&](size_t bytes) { void* p = ws + off; off += (bytes + 255) & ~size_t(255); return p; };
    int*      bcnt    = (int*)carve((size_t)256 * 4);
    int*      bbase   = (int*)carve((size_t)(NBUCK + 1) * 4);
    int*      gcursor = (int*)carve((size_t)256 * 4);
    int*      row_ptr = (int*)carve((size_t)(N + 1) * 4);
    float*    dinv    = (float*)carve((size_t)N * 4);
    unsigned* bkt     = (unsigned*)carve((size_t)E * 4);   // packed (row<<16|col)
    u16*      cols16  = (u16*)carve((size_t)E * 2);
    f16*      w1h     = (f16*)carve((size_t)HID * IN_D * 2);
    f16*      w2h     = (f16*)carve((size_t)IN_D * HID * 2);
    f16*      xs      = (f16*)carve((size_t)(N + 1) * IN_D * 2); // pre-scaled x, +zero row
    f16*      y1h     = (f16*)carve((size_t)(N + 1) * IN_D * 2); // y1, becomes zs in-place (+zero row)
    f16*      zsh     = y1h;

    const int TB = 256;
    const int eblk = (E + 2047) / 2048;   // 391

    // 1) bucketed CSR build
    zero256<<<1, 256, 0, stream>>>(bcnt);
    bucket_hist<<<eblk, TB, 0, stream>>>(row, bcnt, E);
    bucket_scan<<<1, TB, 0, stream>>>(bcnt, bbase, gcursor, NBUCK);
    bucket_place<<<eblk, TB, 0, stream>>>(row, col, gcursor, bkt, E);
    csr_fill<<<NBUCK, TB, 0, stream>>>(bkt, bbase, row_ptr, dinv, cols16, N);

    // 2) prep: weights->f16, xs = dinv(.)x, zero tail rows (needs dinv)
    {
        int total_q = 2 * (HID * IN_D / 4) + N * (DIM / 4) + 64;
        prep_tables<<<(total_q + TB - 1) / TB, TB, 0, stream>>>(
            W1, W2, x, dinv, w1h, w2h, xs, zsh, N);
    }

    // 3) y1 = A' x   (pure gather+add -> f16 out)
    spmm_gather<true, false><<<(N * 32 + TB - 1) / TB, TB, 0, stream>>>(
        row_ptr, cols16, xs, dinv, nullptr, nullptr, y1h, N);

    // 4) zs = dinv (.) [ relu(y1 W1^T + b1) W2^T ]   (fused, in-place over y1)
    mlp_fused<<<(N + 127) / 128, 256, 0, stream>>>(y1h, w1h, b1, w2h, dinv, zsh, N);

    // 5) out = A' z + b2 = dinv (.) (zs_self + sum zs_c) + b2   (fp32 out)
    spmm_gather<false, true><<<(N * 32 + TB - 1) / TB, TB, 0, stream>>>(
        row_ptr, cols16, zsh, dinv, b2, out, nullptr, N);
}

// Round 11
// 143.007 us; speedup vs baseline: 20.0419x; 1.0868x over previous
//
#include <hip/hip_runtime.h>
#include <hip/hip_bf16.h>

#define NNODES 50000   // must stay < 65536 (row/col packed into one u32)
#define DIM 128        // both SPMMs run on 128 dims after the W2 reorder
#define NBUCK 196      // ceil(NNODES/256); bucket b covers rows [b*256, b*256+256)
#define BCAP 8192      // fixed segment capacity per bucket (mean 4081, sd 64 -> +64 sigma)

typedef unsigned short u16;
typedef _Float16 f16;
typedef float  f32x4  __attribute__((ext_vector_type(4)));
typedef _Float16 f16x4v __attribute__((ext_vector_type(4)));
typedef _Float16 f16x8 __attribute__((ext_vector_type(8)));

#define MFMAH(a, b, c) __builtin_amdgcn_mfma_f32_16x16x32_f16((a), (b), (c), 0, 0, 0)

// ---------------- cursor init: cursor[b] = b*BCAP ----------------
__global__ void init_cursor(int* __restrict__ cursor) {
    cursor[threadIdx.x] = (int)threadIdx.x * BCAP;
}

// ---------------- pass B: place packed (row,col) edges into fixed bucket segments ----------------
// LDS-batched: one global atomicAdd per (block,bucket) touched; per-(block,bucket)
// runs are contiguous (~80B store runs instead of random 4B).
__global__ __launch_bounds__(256) void bucket_place(const int* __restrict__ row,
                                                    const int* __restrict__ col,
                                                    int* __restrict__ gcursor,
                                                    unsigned* __restrict__ bkt, int nE) {
    __shared__ int hist[256];
    __shared__ int cur[256];
    int t = threadIdx.x;
    hist[t] = 0;
    __syncthreads();
    unsigned pk[8]; int valid = 0;
    int base_e = blockIdx.x * 2048 + t;
    #pragma unroll
    for (int k = 0; k < 8; ++k) {
        int e = base_e + k * 256;
        if (e < nE) {
            unsigned r = (unsigned)row[e], c = (unsigned)col[e];
            pk[k] = (r << 16) | c;
            valid |= 1 << k;
            atomicAdd(&hist[r >> 8], 1);
        }
    }
    __syncthreads();
    if (hist[t] > 0) cur[t] = atomicAdd(&gcursor[t], hist[t]);
    __syncthreads();
    #pragma unroll
    for (int k = 0; k < 8; ++k) {
        if (valid & (1 << k)) {
            int pos = atomicAdd(&cur[pk[k] >> 24], 1);   // pk>>24 == row>>8
            bkt[pos] = pk[k];
        }
    }
}

// ---------------- pass C: one block per bucket -> row ranges (int2), dinv, cols16 ----------------
// Segmented CSR: cols for bucket b live in [b*BCAP, gcursor[b]); per-row range from
// intra-bucket count+scan. No compact global scan needed.
__global__ __launch_bounds__(256) void csr_fill(const unsigned* __restrict__ bkt,
                                                const int* __restrict__ gcursor,
                                                int2* __restrict__ row_rng,
                                                float* __restrict__ dinv,
                                                u16* __restrict__ cols16, int n) {
    __shared__ int lcnt[256], lscan[256], lcur[256];
    int b = blockIdx.x, t = threadIdx.x;
    int r0 = b << 8;
    int s = b * BCAP, e = gcursor[b];
    lcnt[t] = 0;
    __syncthreads();
    for (int i = s + t; i < e; i += 256)
        atomicAdd(&lcnt[(bkt[i] >> 16) & 255], 1);
    __syncthreads();
    int v = lcnt[t];
    lscan[t] = v;
    __syncthreads();
    for (int off = 1; off < 256; off <<= 1) {
        int u = (t >= off) ? lscan[t - off] : 0;
        __syncthreads();
        lscan[t] += u;
        __syncthreads();
    }
    int gpos = s + lscan[t] - v;          // exclusive prefix within segment
    int r = r0 + t;
    if (r < n) {
        row_rng[r] = make_int2(gpos, gpos + v);
        dinv[r] = rsqrtf((float)(v + 1)); // +1 self loop; deg>=1 so clip no-op
    }
    lcur[t] = gpos;
    __syncthreads();
    for (int i = s + t; i < e; i += 256) {
        unsigned rc = bkt[i];
        int pos = atomicAdd(&lcur[(rc >> 16) & 255], 1);
        cols16[pos] = (u16)(rc & 0xffffu);
    }
}

// ---------------- prep: W1/W2 -> f16, xs = dinv*x (f16), zero rows N of xs/zs ----------------
__global__ __launch_bounds__(256) void prep_tables(
        const float* __restrict__ W1, const float* __restrict__ W2,
        const float* __restrict__ x, const float* __restrict__ dinv,
        f16* __restrict__ w1h, f16* __restrict__ w2h,
        f16* __restrict__ xs, f16* __restrict__ zs, int n) {
    const int WQ = (256 * 128) / 4;       // 8192 quads per weight
    const int XQ = n * (DIM / 4);         // node-feature quads
    int i = blockIdx.x * 256 + threadIdx.x;
    if (i < WQ) {
        float4 v = reinterpret_cast<const float4*>(W1)[i];
        f16x4v o = { (f16)v.x, (f16)v.y, (f16)v.z, (f16)v.w };
        reinterpret_cast<f16x4v*>(w1h)[i] = o;
    } else if (i < 2 * WQ) {
        int j = i - WQ;
        float4 v = reinterpret_cast<const float4*>(W2)[j];
        f16x4v o = { (f16)v.x, (f16)v.y, (f16)v.z, (f16)v.w };
        reinterpret_cast<f16x4v*>(w2h)[j] = o;
    } else {
        int j = i - 2 * WQ;
        if (j < XQ) {
            float d = dinv[j >> 5];
            float4 v = reinterpret_cast<const float4*>(x)[j];
            f16x4v o = { (f16)(d * v.x), (f16)(d * v.y), (f16)(d * v.z), (f16)(d * v.w) };
            reinterpret_cast<f16x4v*>(xs)[j] = o;
        } else if (j < XQ + 32) {          // zero row N of xs (gather tail target)
            f16x4v o = {};
            reinterpret_cast<f16x4v*>(xs)[j] = o;
        } else if (j < XQ + 64) {          // zero row N of zs
            f16x4v o = {};
            reinterpret_cast<f16x4v*>(zs)[XQ + (j - XQ - 32)] = o;
        }
    }
}

// ---------------- CSR SPMM: pre-scaled f16 gather, batched-16, zero-row tail ----------------
// Y[i,:] = dinv[i] * ( Xs[i,:] + sum_j Xs[c_j,:] )  (+ bias)   where Xs = dinv (.) X
template <bool OUT16, bool BIAS>
__global__ __launch_bounds__(256) void spmm_gather(const int2* __restrict__ row_rng,
                         const u16* __restrict__ cols16,
                         const f16* __restrict__ Xs, const float* __restrict__ dinv,
                         const float* __restrict__ bias,
                         float* __restrict__ Y, f16* __restrict__ Yh, int n) {
    int tid = blockIdx.x * blockDim.x + threadIdx.x;
    int i = tid >> 5;        // node
    int l = tid & 31;        // 4-elem slot (DIM/4 == 32)
    if (i >= n) return;
    const f16x4v* X4 = reinterpret_cast<const f16x4v*>(Xs);
    int2 rng = row_rng[i];
    float di = dinv[i];
    f16x4v xv = X4[(size_t)i * 32 + l];           // self term (pre-scaled)
    float4 acc;
    acc.x = (float)xv[0]; acc.y = (float)xv[1];
    acc.z = (float)xv[2]; acc.w = (float)xv[3];
    int s = rng.x, e = rng.y;
    for (int j = s; j < e; j += 16) {
        int c[16];
        #pragma unroll
        for (int t = 0; t < 16; ++t) {
            int idx = j + t;
            bool ok = idx < e;
            int cc = (int)cols16[ok ? idx : (e - 1)];
            c[t] = ok ? cc : n;                   // invalid -> zero row N
        }
        f16x4v g[16];
        #pragma unroll
        for (int t = 0; t < 16; ++t) g[t] = X4[(size_t)c[t] * 32 + l];  // 32 in flight/wave
        #pragma unroll
        for (int t = 0; t < 16; ++t) {
            acc.x += (float)g[t][0];
            acc.y += (float)g[t][1];
            acc.z += (float)g[t][2];
            acc.w += (float)g[t][3];
        }
    }
    acc.x *= di; acc.y *= di; acc.z *= di; acc.w *= di;
    if (BIAS) {
        float4 b = reinterpret_cast<const float4*>(bias)[l];
        acc.x += b.x; acc.y += b.y; acc.z += b.z; acc.w += b.w;
    }
    if (OUT16) {
        f16x4v o = { (f16)acc.x, (f16)acc.y, (f16)acc.z, (f16)acc.w };
        *reinterpret_cast<f16x4v*>(&Yh[(size_t)i * DIM + l * 4]) = o;
    } else {
        reinterpret_cast<float4*>(Y)[(size_t)i * 32 + l] = acc;
    }
}

// ---------------- fused MLP: zs = dinv (.) [ relu(y1 W1^T + b1) W2^T ], all f16 MFMA ----------------
// Barrier-free: each wave owns 32 rows end-to-end; h lives in wave-private LDS.
__global__ __launch_bounds__(256, 2) void mlp_fused(
        const f16* __restrict__ y1, const f16* __restrict__ w1,
        const float* __restrict__ b1, const f16* __restrict__ w2,
        const float* __restrict__ dinv, f16* __restrict__ zs, int M) {
    constexpr int HSTR = 264;                 // 256 + 8 pad: 16B-aligned rows
    __shared__ f16 hl[4][32][HSTR];           // 66 KB -> 2 blocks/CU
    const int wave = threadIdx.x >> 6;
    const int lane = threadIdx.x & 63;
    const int lr = lane & 15;                 // fragment row/col index
    const int lq = lane >> 4;                 // k-quad (8 elems)
    const int mbase = blockIdx.x * 128 + wave * 32;

    // y1 B-frags for this wave's 32 rows, all k=128: read once, reuse all quarters.
    f16x8 yb[2][4];
    #pragma unroll
    for (int nf = 0; nf < 2; ++nf) {
        int r = min(mbase + nf * 16 + lr, M - 1);
        const f16* pr = y1 + (size_t)r * 128 + lq * 8;
        #pragma unroll
        for (int ks = 0; ks < 4; ++ks)
            yb[nf][ks] = *reinterpret_cast<const f16x8*>(pr + ks * 32);
    }

    // ---- phase 1: h = relu(y1 W1^T + b1), 4 quarters of 64 h-cols ----
    #pragma unroll 1
    for (int q = 0; q < 4; ++q) {
        const int hc0 = q * 64;
        f16x8 wa[4][4];
        #pragma unroll
        for (int mf = 0; mf < 4; ++mf) {
            const f16* pw = w1 + (size_t)(hc0 + mf * 16 + lr) * 128 + lq * 8;
            #pragma unroll
            for (int ks = 0; ks < 4; ++ks)
                wa[mf][ks] = *reinterpret_cast<const f16x8*>(pw + ks * 32);
        }
        f32x4 acc[4][2] = {};
        #pragma unroll
        for (int ks = 0; ks < 4; ++ks)
            #pragma unroll
            for (int mf = 0; mf < 4; ++mf)
                #pragma unroll
                for (int nf = 0; nf < 2; ++nf)
                    acc[mf][nf] = MFMAH(wa[mf][ks], yb[nf][ks], acc[mf][nf]);
        #pragma unroll
        for (int mf = 0; mf < 4; ++mf) {
            float4 bb = *reinterpret_cast<const float4*>(&b1[hc0 + mf * 16 + lq * 4]);
            #pragma unroll
            for (int nf = 0; nf < 2; ++nf) {
                f16x4v hv = { (f16)fmaxf(acc[mf][nf][0] + bb.x, 0.f),
                              (f16)fmaxf(acc[mf][nf][1] + bb.y, 0.f),
                              (f16)fmaxf(acc[mf][nf][2] + bb.z, 0.f),
                              (f16)fmaxf(acc[mf][nf][3] + bb.w, 0.f) };
                *reinterpret_cast<f16x4v*>(&hl[wave][nf * 16 + lr][hc0 + mf * 16 + lq * 4]) = hv;
            }
        }
    }

    // ---- phase 2: z = h W2^T  (wave-private LDS reads; no barrier needed) ----
    f32x4 acc2[8][2] = {};
    #pragma unroll 1
    for (int ks = 0; ks < 8; ++ks) {
        f16x8 hb[2];
        #pragma unroll
        for (int nf = 0; nf < 2; ++nf)
            hb[nf] = *reinterpret_cast<const f16x8*>(&hl[wave][nf * 16 + lr][ks * 32 + lq * 8]);
        f16x8 wa2[8];
        #pragma unroll
        for (int mf = 0; mf < 8; ++mf)
            wa2[mf] = *reinterpret_cast<const f16x8*>(w2 + (size_t)(mf * 16 + lr) * 256 + ks * 32 + lq * 8);
        #pragma unroll
        for (int mf = 0; mf < 8; ++mf)
            #pragma unroll
            for (int nf = 0; nf < 2; ++nf)
                acc2[mf][nf] = MFMAH(wa2[mf], hb[nf], acc2[mf][nf]);
    }
    #pragma unroll
    for (int nf = 0; nf < 2; ++nf) {
        int node = mbase + nf * 16 + lr;
        if (node >= M) continue;
        float dn = dinv[node];
        #pragma unroll
        for (int mf = 0; mf < 8; ++mf) {
            f16x4v zv = { (f16)(dn * acc2[mf][nf][0]), (f16)(dn * acc2[mf][nf][1]),
                          (f16)(dn * acc2[mf][nf][2]), (f16)(dn * acc2[mf][nf][3]) };
            *reinterpret_cast<f16x4v*>(zs + (size_t)node * 128 + mf * 16 + lq * 4) = zv;
        }
    }
}

extern "C" void kernel_launch(void* const* d_in, const int* in_sizes, int n_in,
                              void* d_out, int out_size, void* d_ws, size_t ws_size,
                              hipStream_t stream) {
    const float* x  = (const float*)d_in[0];
    const int*   ei = (const int*)d_in[1];
    const float* W1 = (const float*)d_in[2];
    const float* b1 = (const float*)d_in[3];
    const float* W2 = (const float*)d_in[4];
    const float* b2 = (const float*)d_in[5];
    float* out = (float*)d_out;

    const int N = NNODES;
    const int E = in_sizes[1] / 2;
    const int IN_D = 128, HID = 256;
    const int* row = ei;
    const int* col = ei + E;

    // workspace carve-out (aligned to 256B)
    char* ws = (char*)d_ws;
    size_t off = 0;
    auto carve = [&](size_t bytes) { void* p = ws + off; off += (bytes + 255) & ~size_t(255); return p; };
    int*      gcursor = (int*)carve((size_t)256 * 4);
    int2*     row_rng = (int2*)carve((size_t)N * 8);
    float*    dinv    = (float*)carve((size_t)N * 4);
    unsigned* bkt     = (unsigned*)carve((size_t)NBUCK * BCAP * 4); // segmented (row<<16|col)
    u16*      cols16  = (u16*)carve((size_t)NBUCK * BCAP * 2);      // segmented cols
    f16*      w1h     = (f16*)carve((size_t)HID * IN_D * 2);
    f16*      w2h     = (f16*)carve((size_t)IN_D * HID * 2);
    f16*      xs      = (f16*)carve((size_t)(N + 1) * IN_D * 2); // pre-scaled x, +zero row
    f16*      y1h     = (f16*)carve((size_t)(N + 1) * IN_D * 2); // y1, becomes zs in-place (+zero row)
    f16*      zsh     = y1h;

    const int TB = 256;
    const int eblk = (E + 2047) / 2048;   // 391

    // 1) segmented CSR build: init cursors -> place -> fill (no hist, no scan)
    init_cursor<<<1, 256, 0, stream>>>(gcursor);
    bucket_place<<<eblk, TB, 0, stream>>>(row, col, gcursor, bkt, E);
    csr_fill<<<NBUCK, TB, 0, stream>>>(bkt, gcursor, row_rng, dinv, cols16, N);

    // 2) prep: weights->f16, xs = dinv(.)x, zero tail rows (needs dinv)
    {
        int total_q = 2 * (HID * IN_D / 4) + N * (DIM / 4) + 64;
        prep_tables<<<(total_q + TB - 1) / TB, TB, 0, stream>>>(
            W1, W2, x, dinv, w1h, w2h, xs, zsh, N);
    }

    // 3) y1 = A' x   (pure gather+add -> f16 out)
    spmm_gather<true, false><<<(N * 32 + TB - 1) / TB, TB, 0, stream>>>(
        row_rng, cols16, xs, dinv, nullptr, nullptr, y1h, N);

    // 4) zs = dinv (.) [ relu(y1 W1^T + b1) W2^T ]   (fused, in-place over y1)
    mlp_fused<<<(N + 127) / 128, 256, 0, stream>>>(y1h, w1h, b1, w2h, dinv, zsh, N);

    // 5) out = A' z + b2 = dinv (.) (zs_self + sum zs_c) + b2   (fp32 out)
    spmm_gather<false, true><<<(N * 32 + TB - 1) / TB, TB, 0, stream>>>(
        row_rng, cols16, zsh, dinv, b2, out, nullptr, N);
}